// Round 2
// baseline (183.535 us; speedup 1.0000x reference)
//
#include <hip/hip_runtime.h>

#define T_   2048
#define DM   1024
#define H_   16
#define DH   64

typedef unsigned short u16;
typedef __attribute__((ext_vector_type(8))) short bf16x8;   // 8 bf16 = 4 VGPR
typedef __attribute__((ext_vector_type(8))) unsigned short u16x8;
typedef __attribute__((ext_vector_type(4))) float f32x4;

static __device__ __forceinline__ u16 f2b(float f) {
  unsigned int u = __builtin_bit_cast(unsigned int, f);
  u += 0x7fff + ((u >> 16) & 1);   // RNE
  return (u16)(u >> 16);
}

static __device__ __forceinline__ void gll16(const void* g, void* l) {
  __builtin_amdgcn_global_load_lds(
      (const __attribute__((address_space(1))) unsigned int*)g,
      (__attribute__((address_space(3))) unsigned int*)l, 16, 0, 0);
}

// ---------------- conversions ----------------

__global__ __launch_bounds__(256) void k_cvt_x(const float* __restrict__ x,
                                               u16* __restrict__ o) {
  int i = (blockIdx.x * 256 + threadIdx.x) * 8;
  float4 a = *(const float4*)(x + i);
  float4 b = *(const float4*)(x + i + 4);
  u16x8 r;
  r[0] = f2b(a.x); r[1] = f2b(a.y); r[2] = f2b(a.z); r[3] = f2b(a.w);
  r[4] = f2b(b.x); r[5] = f2b(b.y); r[6] = f2b(b.z); r[7] = f2b(b.w);
  *(u16x8*)(o + i) = r;
}

// W [K][N] fp32 -> Wt [N][K] bf16 (64x64 tiles via LDS)
__global__ __launch_bounds__(256) void k_cvt_wt(
    const float* __restrict__ Wq, const float* __restrict__ Wk,
    const float* __restrict__ Wv, const float* __restrict__ Wo,
    u16* __restrict__ oq, u16* __restrict__ ok, u16* __restrict__ ov,
    u16* __restrict__ oo) {
  const float* W; u16* Wt;
  int z = blockIdx.z;
  if (z == 0)      { W = Wq; Wt = oq; }
  else if (z == 1) { W = Wk; Wt = ok; }
  else if (z == 2) { W = Wv; Wt = ov; }
  else             { W = Wo; Wt = oo; }
  __shared__ u16 tile[64][65];
  int k0 = blockIdx.x * 64, n0 = blockIdx.y * 64;
  int r = threadIdx.x >> 2, c0 = (threadIdx.x & 3) * 16;
  const float* src = W + (k0 + r) * DM + n0 + c0;
#pragma unroll
  for (int e = 0; e < 16; e += 4) {
    float4 v = *(const float4*)(src + e);
    tile[r][c0 + e + 0] = f2b(v.x);
    tile[r][c0 + e + 1] = f2b(v.y);
    tile[r][c0 + e + 2] = f2b(v.z);
    tile[r][c0 + e + 3] = f2b(v.w);
  }
  __syncthreads();
  // out row n0+r, cols k0+c0..+15 : Wt[n][k] = W[k][n] = tile[k-k0][n-n0]
  u16x8 a, b;
#pragma unroll
  for (int e = 0; e < 8; ++e) a[e] = tile[c0 + e][r];
#pragma unroll
  for (int e = 0; e < 8; ++e) b[e] = tile[c0 + 8 + e][r];
  u16* dst = Wt + (n0 + r) * DM + k0 + c0;
  *(u16x8*)dst = a;
  *(u16x8*)(dst + 8) = b;
}

// ---------------- GEMM mainloop (C = A[M,K] * Bt[N,K]^T), 128x128 tile ----

static __device__ __forceinline__ void gemm_mainloop(
    const u16* __restrict__ A, const u16* __restrict__ Bt,
    u16* As, u16* Bs, int m0, int n0, f32x4 (&acc)[4][4]) {
  const int tid = threadIdx.x;
  const int w = tid >> 6, lane = tid & 63;
  const int wr = (w >> 1) * 64, wc = (w & 1) * 64;
  for (int k0 = 0; k0 < DM; k0 += 64) {
    // stage A[128][64], Bt-rows[128][64] into linear LDS via global_load_lds
#pragma unroll
    for (int c = 0; c < 4; ++c) {
      int row = w * 32 + c * 8 + (lane >> 3);
      int col = k0 + (lane & 7) * 8;
      gll16(A + (m0 + row) * DM + col, As + (w * 32 + c * 8) * 64);
      gll16(Bt + (n0 + row) * DM + col, Bs + (w * 32 + c * 8) * 64);
    }
    asm volatile("s_waitcnt vmcnt(0)" ::: "memory");
    __syncthreads();
#pragma unroll
    for (int kk = 0; kk < 2; ++kk) {
      bf16x8 a[4], b[4];
#pragma unroll
      for (int mi = 0; mi < 4; ++mi)
        a[mi] = *(const bf16x8*)(As + (wr + mi * 16 + (lane & 15)) * 64 +
                                 kk * 32 + (lane >> 4) * 8);
#pragma unroll
      for (int ni = 0; ni < 4; ++ni)
        b[ni] = *(const bf16x8*)(Bs + (wc + ni * 16 + (lane & 15)) * 64 +
                                 kk * 32 + (lane >> 4) * 8);
#pragma unroll
      for (int mi = 0; mi < 4; ++mi)
#pragma unroll
        for (int ni = 0; ni < 4; ++ni)
          acc[mi][ni] = __builtin_amdgcn_mfma_f32_16x16x32_bf16(
              a[mi], b[ni], acc[mi][ni], 0, 0, 0);
    }
    __syncthreads();
  }
}

// QKV projections: z selects Wq/Wk/Wv.  Q,K scattered [b,h,t,d]; V as [b,h,d,t]
__global__ __launch_bounds__(256) void k_gemm_qkv(
    const u16* __restrict__ X, const u16* __restrict__ Wqt,
    const u16* __restrict__ Wkt, const u16* __restrict__ Wvt,
    u16* __restrict__ Qg, u16* __restrict__ Kg, u16* __restrict__ Vtg) {
  __shared__ u16 As[128 * 64];
  __shared__ u16 Bs[128 * 64];
  const int z = blockIdx.z;
  const u16* Bt = (z == 0) ? Wqt : (z == 1) ? Wkt : Wvt;
  u16* out = (z == 0) ? Qg : (z == 1) ? Kg : Vtg;
  const int m0 = blockIdx.x * 128, n0 = blockIdx.y * 128;
  f32x4 acc[4][4];
#pragma unroll
  for (int mi = 0; mi < 4; ++mi)
#pragma unroll
    for (int ni = 0; ni < 4; ++ni) acc[mi][ni] = (f32x4){0.f, 0.f, 0.f, 0.f};
  gemm_mainloop(X, Bt, As, Bs, m0, n0, acc);
  const int lane = threadIdx.x & 63, w = threadIdx.x >> 6;
  const int wr = (w >> 1) * 64, wc = (w & 1) * 64;
  const bool isV = (z == 2);
#pragma unroll
  for (int mi = 0; mi < 4; ++mi)
#pragma unroll
    for (int ni = 0; ni < 4; ++ni)
#pragma unroll
      for (int r = 0; r < 4; ++r) {
        int m = m0 + wr + mi * 16 + (lane >> 4) * 4 + r;
        int n = n0 + wc + ni * 16 + (lane & 15);
        int b = m >> 11, t = m & 2047, h = n >> 6, d = n & 63;
        int idx = isV ? ((b * H_ + h) * DH + d) * T_ + t
                      : ((b * H_ + h) * T_ + t) * DH + d;
        out[idx] = f2b(acc[mi][ni][r]);
      }
}

// Output projection: out = Y[M,DM] * Wot^T + bo  (fp32 out)
__global__ __launch_bounds__(256) void k_gemm_out(
    const u16* __restrict__ Y, const u16* __restrict__ Wot,
    const float* __restrict__ bo, float* __restrict__ out) {
  __shared__ u16 As[128 * 64];
  __shared__ u16 Bs[128 * 64];
  const int m0 = blockIdx.x * 128, n0 = blockIdx.y * 128;
  f32x4 acc[4][4];
#pragma unroll
  for (int mi = 0; mi < 4; ++mi)
#pragma unroll
    for (int ni = 0; ni < 4; ++ni) acc[mi][ni] = (f32x4){0.f, 0.f, 0.f, 0.f};
  gemm_mainloop(Y, Wot, As, Bs, m0, n0, acc);
  const int lane = threadIdx.x & 63, w = threadIdx.x >> 6;
  const int wr = (w >> 1) * 64, wc = (w & 1) * 64;
#pragma unroll
  for (int mi = 0; mi < 4; ++mi)
#pragma unroll
    for (int ni = 0; ni < 4; ++ni)
#pragma unroll
      for (int r = 0; r < 4; ++r) {
        int m = m0 + wr + mi * 16 + (lane >> 4) * 4 + r;
        int n = n0 + wc + ni * 16 + (lane & 15);
        out[m * DM + n] = acc[mi][ni][r] + bo[n];
      }
}

// ---------------- flash attention (causal) ----------------
// block = (bh, 64 q rows), 4 waves x 16 rows.  KV tiles of 64.
__global__ __launch_bounds__(256) void k_attn(
    const u16* __restrict__ Qg, const u16* __restrict__ Kg,
    const u16* __restrict__ Vtg, u16* __restrict__ Yg) {
  __shared__ u16 Kl[64][72];       // K[j][d], pad 8 -> 2-way-free banks
  __shared__ u16 Vl[64][72];       // V^T: Vl[d][j]
  __shared__ u16 Pl[4][16][72];    // per-wave P[q][j]
  const int bh = blockIdx.x;       // 0..31
  const int q0 = blockIdx.y * 64;
  const int tid = threadIdx.x, w = tid >> 6, lane = tid & 63;
  const u16* Qb = Qg + bh * (T_ * DH);
  const u16* Kb = Kg + bh * (T_ * DH);
  const u16* Vb = Vtg + bh * (DH * T_);

  const int qrow = q0 + w * 16 + (lane & 15);
  bf16x8 qf0 = *(const bf16x8*)(Qb + qrow * DH + (lane >> 4) * 8);
  bf16x8 qf1 = *(const bf16x8*)(Qb + qrow * DH + 32 + (lane >> 4) * 8);

  f32x4 Yacc[4];
#pragma unroll
  for (int dt = 0; dt < 4; ++dt) Yacc[dt] = (f32x4){0.f, 0.f, 0.f, 0.f};
  float mrow[4], lrow[4];
#pragma unroll
  for (int r = 0; r < 4; ++r) { mrow[r] = -1e30f; lrow[r] = 0.f; }

  const int srow = tid >> 2, sc = (tid & 3) * 16;   // staging: row, col-chunk
  const int qbase = q0 + w * 16 + (lane >> 4) * 4;  // this lane's 4 q rows

  for (int j0 = 0; j0 <= q0 + 63; j0 += 64) {
    __syncthreads();   // previous tile fully consumed
    {  // stage K rows j0+srow and V^T rows d=srow (cols j0+sc..)
      const u16* gk = Kb + (j0 + srow) * DH + sc;
      u16x8 t0 = *(const u16x8*)(gk);
      u16x8 t1 = *(const u16x8*)(gk + 8);
      const u16* gv = Vb + srow * T_ + j0 + sc;
      u16x8 t2 = *(const u16x8*)(gv);
      u16x8 t3 = *(const u16x8*)(gv + 8);
      *(u16x8*)&Kl[srow][sc] = t0;
      *(u16x8*)&Kl[srow][sc + 8] = t1;
      *(u16x8*)&Vl[srow][sc] = t2;
      *(u16x8*)&Vl[srow][sc + 8] = t3;
    }
    __syncthreads();

    // ---- scores S = Q * K^T  (4 jt sub-tiles of 16 cols) ----
    f32x4 s[4];
#pragma unroll
    for (int jt = 0; jt < 4; ++jt) {
      bf16x8 k0f = *(const bf16x8*)(&Kl[jt * 16 + (lane & 15)][(lane >> 4) * 8]);
      bf16x8 k1f = *(const bf16x8*)(&Kl[jt * 16 + (lane & 15)][32 + (lane >> 4) * 8]);
      f32x4 z = (f32x4){0.f, 0.f, 0.f, 0.f};
      z = __builtin_amdgcn_mfma_f32_16x16x32_bf16(qf0, k0f, z, 0, 0, 0);
      z = __builtin_amdgcn_mfma_f32_16x16x32_bf16(qf1, k1f, z, 0, 0, 0);
      s[jt] = z;
    }
    // scale + causal mask
#pragma unroll
    for (int jt = 0; jt < 4; ++jt)
#pragma unroll
      for (int r = 0; r < 4; ++r) {
        int kidx = j0 + jt * 16 + (lane & 15);
        float sv = s[jt][r] * 0.125f;
        if (kidx > qbase + r) sv = -1e30f;
        s[jt][r] = sv;
      }
    // ---- online softmax (per register-row r, 16-lane group reduce) ----
    float alpha[4];
#pragma unroll
    for (int r = 0; r < 4; ++r) {
      float mt = fmaxf(fmaxf(s[0][r], s[1][r]), fmaxf(s[2][r], s[3][r]));
      mt = fmaxf(mt, __shfl_xor(mt, 1));
      mt = fmaxf(mt, __shfl_xor(mt, 2));
      mt = fmaxf(mt, __shfl_xor(mt, 4));
      mt = fmaxf(mt, __shfl_xor(mt, 8));
      float mn = fmaxf(mrow[r], mt);
      alpha[r] = __expf(mrow[r] - mn);
      mrow[r] = mn;
      float ps = 0.f;
#pragma unroll
      for (int jt = 0; jt < 4; ++jt) {
        float p = __expf(s[jt][r] - mn);
        s[jt][r] = p;
        ps += p;
      }
      ps += __shfl_xor(ps, 1);
      ps += __shfl_xor(ps, 2);
      ps += __shfl_xor(ps, 4);
      ps += __shfl_xor(ps, 8);
      lrow[r] = lrow[r] * alpha[r] + ps;
    }
#pragma unroll
    for (int dt = 0; dt < 4; ++dt)
#pragma unroll
      for (int r = 0; r < 4; ++r) Yacc[dt][r] *= alpha[r];
    // ---- P (C-layout) -> LDS -> A-layout ----
#pragma unroll
    for (int jt = 0; jt < 4; ++jt)
#pragma unroll
      for (int r = 0; r < 4; ++r)
        Pl[w][(lane >> 4) * 4 + r][jt * 16 + (lane & 15)] = f2b(s[jt][r]);
    asm volatile("s_waitcnt lgkmcnt(0)" ::: "memory");
    // ---- PV ----
#pragma unroll
    for (int kk = 0; kk < 2; ++kk) {
      bf16x8 pf = *(const bf16x8*)(&Pl[w][lane & 15][kk * 32 + (lane >> 4) * 8]);
#pragma unroll
      for (int dt = 0; dt < 4; ++dt) {
        bf16x8 vf =
            *(const bf16x8*)(&Vl[dt * 16 + (lane & 15)][kk * 32 + (lane >> 4) * 8]);
        Yacc[dt] = __builtin_amdgcn_mfma_f32_16x16x32_bf16(pf, vf, Yacc[dt], 0, 0, 0);
      }
    }
  }
  // ---- epilogue: normalize, write y [b,t, h*64+d] bf16 ----
  const int row_b = (bh >> 4) * T_;
  const int hcol = (bh & 15) * DH;
#pragma unroll
  for (int dt = 0; dt < 4; ++dt)
#pragma unroll
    for (int r = 0; r < 4; ++r) {
      float val = Yacc[dt][r] / lrow[r];
      int m = row_b + qbase + r;
      int n = hcol + dt * 16 + (lane & 15);
      Yg[m * DM + n] = f2b(val);
    }
}

// ---------------- launch ----------------

extern "C" void kernel_launch(void* const* d_in, const int* in_sizes, int n_in,
                              void* d_out, int out_size, void* d_ws,
                              size_t ws_size, hipStream_t stream) {
  const float* x  = (const float*)d_in[0];
  const float* Wq = (const float*)d_in[1];
  const float* Wk = (const float*)d_in[2];
  const float* Wv = (const float*)d_in[3];
  const float* Wo = (const float*)d_in[4];
  const float* bo = (const float*)d_in[5];
  float* out = (float*)d_out;
  char* ws = (char*)d_ws;

  u16* xb  = (u16*)(ws);                    // 8 MiB [4096][1024]
  u16* wqt = (u16*)(ws + (8ull << 20));     // 2 MiB each, [N][K]
  u16* wkt = (u16*)(ws + (10ull << 20));
  u16* wvt = (u16*)(ws + (12ull << 20));
  u16* wot = (u16*)(ws + (14ull << 20));
  u16* Qg  = (u16*)(ws + (16ull << 20));    // 8 MiB [b,h,t,d]
  u16* Kg  = (u16*)(ws + (24ull << 20));    // 8 MiB [b,h,t,d]
  u16* Vtg = (u16*)(ws + (32ull << 20));    // 8 MiB [b,h,d,t]
  u16* Yg  = (u16*)(ws + (40ull << 20));    // 8 MiB [4096][1024]

  k_cvt_x<<<2048, 256, 0, stream>>>(x, xb);
  k_cvt_wt<<<dim3(16, 16, 4), 256, 0, stream>>>(Wq, Wk, Wv, Wo, wqt, wkt, wvt, wot);
  k_gemm_qkv<<<dim3(32, 8, 3), 256, 0, stream>>>(xb, wqt, wkt, wvt, Qg, Kg, Vtg);
  k_attn<<<dim3(32, 32), 256, 0, stream>>>(Qg, Kg, Vtg, Yg);
  k_gemm_out<<<dim3(32, 8), 256, 0, stream>>>(Yg, wot, bo, out);
}

// Round 3
// 142.310 us; speedup vs baseline: 1.2897x; 1.2897x over previous
//
#include <hip/hip_runtime.h>

#define T_   2048
#define DM   1024
#define H_   16
#define DH   64

typedef unsigned short u16;
typedef unsigned int u32;
typedef __attribute__((ext_vector_type(8))) short bf16x8;   // 8 bf16 = 4 VGPR
typedef __attribute__((ext_vector_type(8))) unsigned short u16x8;
typedef __attribute__((ext_vector_type(4))) float f32x4;
typedef __attribute__((ext_vector_type(16))) float f32x16;
typedef __attribute__((ext_vector_type(4))) unsigned int u32x4;
typedef __attribute__((ext_vector_type(2))) unsigned int u32x2;

static __device__ __forceinline__ u16 f2b(float f) {
  unsigned int u = __builtin_bit_cast(unsigned int, f);
  u += 0x7fff + ((u >> 16) & 1);   // RNE
  return (u16)(u >> 16);
}

static __device__ __forceinline__ u32 cvtpk(float a, float b) {
  u32 d;
  asm("v_cvt_pk_bf16_f32 %0, %1, %2" : "=v"(d) : "v"(a), "v"(b));
  return d;   // lo = bf16(a), hi = bf16(b)
}

static __device__ __forceinline__ void gll16(const void* g, void* l) {
  __builtin_amdgcn_global_load_lds(
      (const __attribute__((address_space(1))) unsigned int*)g,
      (__attribute__((address_space(3))) unsigned int*)l, 16, 0, 0);
}

// ---------------- conversions ----------------

__global__ __launch_bounds__(256) void k_cvt_x(const float* __restrict__ x,
                                               u16* __restrict__ o) {
  int i = (blockIdx.x * 256 + threadIdx.x) * 8;
  float4 a = *(const float4*)(x + i);
  float4 b = *(const float4*)(x + i + 4);
  u16x8 r;
  r[0] = f2b(a.x); r[1] = f2b(a.y); r[2] = f2b(a.z); r[3] = f2b(a.w);
  r[4] = f2b(b.x); r[5] = f2b(b.y); r[6] = f2b(b.z); r[7] = f2b(b.w);
  *(u16x8*)(o + i) = r;
}

// W [K][N] fp32 -> Wt [N][K] bf16 (64x64 tiles via LDS).
// Wq is pre-scaled by 0.125*log2(e) so attention scores are directly in the
// exp2 domain (softmax scale fused into the projection).
__global__ __launch_bounds__(256) void k_cvt_wt(
    const float* __restrict__ Wq, const float* __restrict__ Wk,
    const float* __restrict__ Wv, const float* __restrict__ Wo,
    u16* __restrict__ oq, u16* __restrict__ ok, u16* __restrict__ ov,
    u16* __restrict__ oo) {
  const float* W; u16* Wt;
  int z = blockIdx.z;
  if (z == 0)      { W = Wq; Wt = oq; }
  else if (z == 1) { W = Wk; Wt = ok; }
  else if (z == 2) { W = Wv; Wt = ov; }
  else             { W = Wo; Wt = oo; }
  const float wsc = (z == 0) ? 0.1803368801111204f : 1.0f;  // 0.125*log2e
  __shared__ u16 tile[64][65];
  int k0 = blockIdx.x * 64, n0 = blockIdx.y * 64;
  int r = threadIdx.x >> 2, c0 = (threadIdx.x & 3) * 16;
  const float* src = W + (k0 + r) * DM + n0 + c0;
#pragma unroll
  for (int e = 0; e < 16; e += 4) {
    float4 v = *(const float4*)(src + e);
    tile[r][c0 + e + 0] = f2b(v.x * wsc);
    tile[r][c0 + e + 1] = f2b(v.y * wsc);
    tile[r][c0 + e + 2] = f2b(v.z * wsc);
    tile[r][c0 + e + 3] = f2b(v.w * wsc);
  }
  __syncthreads();
  u16x8 a, b;
#pragma unroll
  for (int e = 0; e < 8; ++e) a[e] = tile[c0 + e][r];
#pragma unroll
  for (int e = 0; e < 8; ++e) b[e] = tile[c0 + 8 + e][r];
  u16* dst = Wt + (n0 + r) * DM + k0 + c0;
  *(u16x8*)dst = a;
  *(u16x8*)(dst + 8) = b;
}

// ---------------- GEMM mainloop (C = A[M,K] * Bt[N,K]^T), 128x128 tile ----

static __device__ __forceinline__ void gemm_mainloop(
    const u16* __restrict__ A, const u16* __restrict__ Bt,
    u16* As, u16* Bs, int m0, int n0, f32x4 (&acc)[4][4]) {
  const int tid = threadIdx.x;
  const int w = tid >> 6, lane = tid & 63;
  const int wr = (w >> 1) * 64, wc = (w & 1) * 64;
  for (int k0 = 0; k0 < DM; k0 += 64) {
#pragma unroll
    for (int c = 0; c < 4; ++c) {
      int row = w * 32 + c * 8 + (lane >> 3);
      int col = k0 + (lane & 7) * 8;
      gll16(A + (m0 + row) * DM + col, As + (w * 32 + c * 8) * 64);
      gll16(Bt + (n0 + row) * DM + col, Bs + (w * 32 + c * 8) * 64);
    }
    asm volatile("s_waitcnt vmcnt(0)" ::: "memory");
    __syncthreads();
#pragma unroll
    for (int kk = 0; kk < 2; ++kk) {
      bf16x8 a[4], b[4];
#pragma unroll
      for (int mi = 0; mi < 4; ++mi)
        a[mi] = *(const bf16x8*)(As + (wr + mi * 16 + (lane & 15)) * 64 +
                                 kk * 32 + (lane >> 4) * 8);
#pragma unroll
      for (int ni = 0; ni < 4; ++ni)
        b[ni] = *(const bf16x8*)(Bs + (wc + ni * 16 + (lane & 15)) * 64 +
                                 kk * 32 + (lane >> 4) * 8);
#pragma unroll
      for (int mi = 0; mi < 4; ++mi)
#pragma unroll
        for (int ni = 0; ni < 4; ++ni)
          acc[mi][ni] = __builtin_amdgcn_mfma_f32_16x16x32_bf16(
              a[mi], b[ni], acc[mi][ni], 0, 0, 0);
    }
    __syncthreads();
  }
}

// QKV projections: z selects Wq/Wk/Wv.  Q,K scattered [b,h,t,d]; V as [b,h,d,t]
__global__ __launch_bounds__(256) void k_gemm_qkv(
    const u16* __restrict__ X, const u16* __restrict__ Wqt,
    const u16* __restrict__ Wkt, const u16* __restrict__ Wvt,
    u16* __restrict__ Qg, u16* __restrict__ Kg, u16* __restrict__ Vtg) {
  __shared__ u16 As[128 * 64];
  __shared__ u16 Bs[128 * 64];
  const int z = blockIdx.z;
  const u16* Bt = (z == 0) ? Wqt : (z == 1) ? Wkt : Wvt;
  u16* out = (z == 0) ? Qg : (z == 1) ? Kg : Vtg;
  const int m0 = blockIdx.x * 128, n0 = blockIdx.y * 128;
  f32x4 acc[4][4];
#pragma unroll
  for (int mi = 0; mi < 4; ++mi)
#pragma unroll
    for (int ni = 0; ni < 4; ++ni) acc[mi][ni] = (f32x4){0.f, 0.f, 0.f, 0.f};
  gemm_mainloop(X, Bt, As, Bs, m0, n0, acc);
  const int lane = threadIdx.x & 63, w = threadIdx.x >> 6;
  const int wr = (w >> 1) * 64, wc = (w & 1) * 64;
  const bool isV = (z == 2);
#pragma unroll
  for (int mi = 0; mi < 4; ++mi)
#pragma unroll
    for (int ni = 0; ni < 4; ++ni)
#pragma unroll
      for (int r = 0; r < 4; ++r) {
        int m = m0 + wr + mi * 16 + (lane >> 4) * 4 + r;
        int n = n0 + wc + ni * 16 + (lane & 15);
        int b = m >> 11, t = m & 2047, h = n >> 6, d = n & 63;
        int idx = isV ? ((b * H_ + h) * DH + d) * T_ + t
                      : ((b * H_ + h) * T_ + t) * DH + d;
        out[idx] = f2b(acc[mi][ni][r]);
      }
}

// Output projection: out = Y[M,DM] * Wot^T + bo  (fp32 out)
__global__ __launch_bounds__(256) void k_gemm_out(
    const u16* __restrict__ Y, const u16* __restrict__ Wot,
    const float* __restrict__ bo, float* __restrict__ out) {
  __shared__ u16 As[128 * 64];
  __shared__ u16 Bs[128 * 64];
  const int m0 = blockIdx.x * 128, n0 = blockIdx.y * 128;
  f32x4 acc[4][4];
#pragma unroll
  for (int mi = 0; mi < 4; ++mi)
#pragma unroll
    for (int ni = 0; ni < 4; ++ni) acc[mi][ni] = (f32x4){0.f, 0.f, 0.f, 0.f};
  gemm_mainloop(Y, Wot, As, Bs, m0, n0, acc);
  const int lane = threadIdx.x & 63, w = threadIdx.x >> 6;
  const int wr = (w >> 1) * 64, wc = (w & 1) * 64;
#pragma unroll
  for (int mi = 0; mi < 4; ++mi)
#pragma unroll
    for (int ni = 0; ni < 4; ++ni)
#pragma unroll
      for (int r = 0; r < 4; ++r) {
        int m = m0 + wr + mi * 16 + (lane >> 4) * 4 + r;
        int n = n0 + wc + ni * 16 + (lane & 15);
        out[m * DM + n] = acc[mi][ni][r] + bo[n];
      }
}

// ---------------- flash attention (causal), swapped-operand 32x32 ----------
// Block = 4 waves x 32 q-rows = 128 q-rows.  KV tiles of 64.
// QK^T computed as mfma(K, Q) -> S^T (lane&31 = q, regs = j): softmax is
// lane-local except one shfl_xor(32).  PV computed as mfma(V^T, P^T) -> O^T
// (lane&31 = q, regs = d): rescale is a per-lane scalar.
// K/V tiles in LDS with XOR swizzle byte ^= (row&7)<<4 (G4 fix).
__global__ __launch_bounds__(256) void k_attn(
    const u16* __restrict__ Qg, const u16* __restrict__ Kg,
    const u16* __restrict__ Vtg, u16* __restrict__ Yg) {
  __shared__ char Kl[64 * 128];   // [j][d] bf16, swizzled
  __shared__ char Vl[64 * 128];   // [d][j] bf16, swizzled
  const int bh = blockIdx.x;              // bh%8 -> XCD: K/V L2-local per bh
  const int qt = 15 - blockIdx.y;         // long-first (LPT) remap
  const int q0 = qt * 128;
  const int tid = threadIdx.x, w = tid >> 6, lane = tid & 63;
  const int hi = lane >> 5, qq = lane & 31;
  const u16* Qb = Qg + bh * (T_ * DH);
  const u16* Kb = Kg + bh * (T_ * DH);
  const u16* Vb = Vtg + bh * (DH * T_);
  const int qrow = q0 + w * 32 + qq;

  // Q B-frags: B[col=q][k = kb*16 + hi*8 + e]
  bf16x8 qf[4];
#pragma unroll
  for (int kb = 0; kb < 4; ++kb)
    qf[kb] = *(const bf16x8*)(Qb + qrow * DH + kb * 16 + hi * 8);

  f32x16 o0, o1;                 // O^T: d = (r&3)+8*(r>>2)+4*hi (+32 for o1)
#pragma unroll
  for (int r = 0; r < 16; ++r) { o0[r] = 0.f; o1[r] = 0.f; }
  float m = -1e30f, lp = 0.f;    // running max / partial denom (own 32 j's)

  const int nt = 2 * qt + 2;               // staged tiles per block
  const int nfull = 2 * qt + (w >> 1);     // tiles before this wave's diagonal
  const int sr = tid >> 3, sc = tid & 7;   // staging row / 16B col
  const int swz0 = (sr * 128 + sc * 16) ^ ((sr & 7) << 4);
  const int swz1 = ((sr + 32) * 128 + sc * 16) ^ ((sr & 7) << 4);

  // async-STAGE split (T14): loads for tile t+1 issued before compute of t
  u32x4 kr0 = *(const u32x4*)(Kb + sr * DH + sc * 8);
  u32x4 kr1 = *(const u32x4*)(Kb + (sr + 32) * DH + sc * 8);
  u32x4 vr0 = *(const u32x4*)(Vb + sr * T_ + sc * 8);
  u32x4 vr1 = *(const u32x4*)(Vb + (sr + 32) * T_ + sc * 8);

  for (int t = 0; t < nt; ++t) {
    __syncthreads();                       // prev tile fully consumed
    *(u32x4*)(Kl + swz0) = kr0;
    *(u32x4*)(Kl + swz1) = kr1;
    *(u32x4*)(Vl + swz0) = vr0;
    *(u32x4*)(Vl + swz1) = vr1;
    __syncthreads();                       // tile visible
    if (t + 1 < nt) {                      // prefetch next tile into regs
      const int jn = (t + 1) * 64;
      kr0 = *(const u32x4*)(Kb + (jn + sr) * DH + sc * 8);
      kr1 = *(const u32x4*)(Kb + (jn + sr + 32) * DH + sc * 8);
      vr0 = *(const u32x4*)(Vb + sr * T_ + jn + sc * 8);
      vr1 = *(const u32x4*)(Vb + (sr + 32) * T_ + jn + sc * 8);
    }
    if (t > nfull) continue;               // wave-uniform guard
    const int j0 = t * 64;

    // ---- S^T = K * Q^T : two 32-j halves ----
    f32x16 s0, s1;
#pragma unroll
    for (int r = 0; r < 16; ++r) { s0[r] = 0.f; s1[r] = 0.f; }
#pragma unroll
    for (int kb = 0; kb < 4; ++kb) {
      const int cb = (kb * 2 + hi) * 16;
      bf16x8 ka0 = *(const bf16x8*)(Kl + ((qq * 128 + cb) ^ ((qq & 7) << 4)));
      s0 = __builtin_amdgcn_mfma_f32_32x32x16_bf16(ka0, qf[kb], s0, 0, 0, 0);
      bf16x8 ka1 =
          *(const bf16x8*)(Kl + (((qq + 32) * 128 + cb) ^ ((qq & 7) << 4)));
      s1 = __builtin_amdgcn_mfma_f32_32x32x16_bf16(ka1, qf[kb], s1, 0, 0, 0);
    }
    // ---- causal mask: only the diagonal tile ----
    if (t == nfull) {
#pragma unroll
      for (int r = 0; r < 16; ++r) {
        const int cr = (r & 3) + 8 * (r >> 2) + 4 * hi;
        if (j0 + cr > qrow) s0[r] = -1e30f;
        if (j0 + 32 + cr > qrow) s1[r] = -1e30f;
      }
    }
    // ---- online softmax, exp2 domain (scale folded into Wq) ----
    float mt = s0[0];
#pragma unroll
    for (int r = 1; r < 16; ++r) mt = fmaxf(mt, s0[r]);
#pragma unroll
    for (int r = 0; r < 16; ++r) mt = fmaxf(mt, s1[r]);
    mt = fmaxf(mt, __shfl_xor(mt, 32));
    if (__any(mt > m + 8.f)) {             // defer-max (T13, THR=8)
      const float mn = fmaxf(m, mt);
      const float al = __builtin_amdgcn_exp2f(m - mn);
      m = mn;
#pragma unroll
      for (int r = 0; r < 16; ++r) { o0[r] *= al; o1[r] *= al; }
      lp *= al;
    }
#pragma unroll
    for (int r = 0; r < 16; ++r) {
      s0[r] = __builtin_amdgcn_exp2f(s0[r] - m);
      s1[r] = __builtin_amdgcn_exp2f(s1[r] - m);
    }
    float ps = 0.f;
#pragma unroll
    for (int r = 0; r < 16; ++r) ps += s0[r] + s1[r];
    lp += ps;
    // ---- P^T B-frags via cvt_pk + permlane32_swap (T12) ----
    bf16x8 pb[4];
#define MKCH(DST, S, RB)                                                     \
  {                                                                          \
    u32 a01 = cvtpk(S[RB + 0], S[RB + 1]);                                   \
    u32 a23 = cvtpk(S[RB + 2], S[RB + 3]);                                   \
    u32 a45 = cvtpk(S[RB + 4], S[RB + 5]);                                   \
    u32 a67 = cvtpk(S[RB + 6], S[RB + 7]);                                   \
    asm volatile("v_permlane32_swap_b32 %0, %1" : "+v"(a01), "+v"(a45));     \
    asm volatile("v_permlane32_swap_b32 %0, %1" : "+v"(a23), "+v"(a67));     \
    u32x4 t4;                                                                \
    t4[0] = a01; t4[1] = a23; t4[2] = a45; t4[3] = a67;                      \
    DST = __builtin_bit_cast(bf16x8, t4);                                    \
  }
    MKCH(pb[0], s0, 0)
    MKCH(pb[1], s0, 8)
    MKCH(pb[2], s1, 0)
    MKCH(pb[3], s1, 8)
#undef MKCH
    // ---- O^T += V^T * P^T ----
#pragma unroll
    for (int jc = 0; jc < 4; ++jc) {
      const int cb = (jc * 2 + hi) * 16;
      bf16x8 va0 = *(const bf16x8*)(Vl + ((qq * 128 + cb) ^ ((qq & 7) << 4)));
      o0 = __builtin_amdgcn_mfma_f32_32x32x16_bf16(va0, pb[jc], o0, 0, 0, 0);
      bf16x8 va1 =
          *(const bf16x8*)(Vl + (((qq + 32) * 128 + cb) ^ ((qq & 7) << 4)));
      o1 = __builtin_amdgcn_mfma_f32_32x32x16_bf16(va1, pb[jc], o1, 0, 0, 0);
    }
  }
  // ---- epilogue: combine denom halves, normalize, write bf16 ----
  lp += __shfl_xor(lp, 32);
  const float rl = 1.0f / lp;
  const int obase = ((bh >> 4) * T_ + qrow) * DM + (bh & 15) * DH;
#pragma unroll
  for (int g = 0; g < 4; ++g) {
    u32x2 st;
    st[0] = cvtpk(o0[g * 4 + 0] * rl, o0[g * 4 + 1] * rl);
    st[1] = cvtpk(o0[g * 4 + 2] * rl, o0[g * 4 + 3] * rl);
    *(u32x2*)(Yg + obase + g * 8 + hi * 4) = st;
    st[0] = cvtpk(o1[g * 4 + 0] * rl, o1[g * 4 + 1] * rl);
    st[1] = cvtpk(o1[g * 4 + 2] * rl, o1[g * 4 + 3] * rl);
    *(u32x2*)(Yg + obase + 32 + g * 8 + hi * 4) = st;
  }
}

// ---------------- launch ----------------

extern "C" void kernel_launch(void* const* d_in, const int* in_sizes, int n_in,
                              void* d_out, int out_size, void* d_ws,
                              size_t ws_size, hipStream_t stream) {
  const float* x  = (const float*)d_in[0];
  const float* Wq = (const float*)d_in[1];
  const float* Wk = (const float*)d_in[2];
  const float* Wv = (const float*)d_in[3];
  const float* Wo = (const float*)d_in[4];
  const float* bo = (const float*)d_in[5];
  float* out = (float*)d_out;
  char* ws = (char*)d_ws;

  u16* xb  = (u16*)(ws);                    // 8 MiB [4096][1024]
  u16* wqt = (u16*)(ws + (8ull << 20));     // 2 MiB each, [N][K]
  u16* wkt = (u16*)(ws + (10ull << 20));
  u16* wvt = (u16*)(ws + (12ull << 20));
  u16* wot = (u16*)(ws + (14ull << 20));
  u16* Qg  = (u16*)(ws + (16ull << 20));    // 8 MiB [b,h,t,d]
  u16* Kg  = (u16*)(ws + (24ull << 20));    // 8 MiB [b,h,t,d]
  u16* Vtg = (u16*)(ws + (32ull << 20));    // 8 MiB [b,h,d,t]
  u16* Yg  = (u16*)(ws + (40ull << 20));    // 8 MiB [4096][1024]

  k_cvt_x<<<2048, 256, 0, stream>>>(x, xb);
  k_cvt_wt<<<dim3(16, 16, 4), 256, 0, stream>>>(Wq, Wk, Wv, Wo, wqt, wkt, wvt, wot);
  k_gemm_qkv<<<dim3(32, 8, 3), 256, 0, stream>>>(xb, wqt, wkt, wvt, Qg, Kg, Vtg);
  k_attn<<<dim3(32, 16), 256, 0, stream>>>(Qg, Kg, Vtg, Yg);
  k_gemm_out<<<dim3(32, 8), 256, 0, stream>>>(Yg, wot, bo, out);
}

// Round 4
// 139.044 us; speedup vs baseline: 1.3200x; 1.0235x over previous
//
#include <hip/hip_runtime.h>

#define T_   2048
#define DM   1024
#define H_   16
#define DH   64

typedef unsigned short u16;
typedef unsigned int u32;
typedef __attribute__((ext_vector_type(8))) short bf16x8;   // 8 bf16 = 4 VGPR
typedef __attribute__((ext_vector_type(8))) unsigned short u16x8;
typedef __attribute__((ext_vector_type(4))) float f32x4;
typedef __attribute__((ext_vector_type(16))) float f32x16;
typedef __attribute__((ext_vector_type(4))) unsigned int u32x4;
typedef __attribute__((ext_vector_type(2))) unsigned int u32x2;

static __device__ __forceinline__ u16 f2b(float f) {
  unsigned int u = __builtin_bit_cast(unsigned int, f);
  u += 0x7fff + ((u >> 16) & 1);   // RNE
  return (u16)(u >> 16);
}

static __device__ __forceinline__ u32 cvtpk(float a, float b) {
  u32 d;
  asm("v_cvt_pk_bf16_f32 %0, %1, %2" : "=v"(d) : "v"(a), "v"(b));
  return d;   // lo = bf16(a), hi = bf16(b)
}

static __device__ __forceinline__ void gll16(const void* g, void* l) {
  __builtin_amdgcn_global_load_lds(
      (const __attribute__((address_space(1))) unsigned int*)g,
      (__attribute__((address_space(3))) unsigned int*)l, 16, 0, 0);
}

#define BARRIER()                                  \
  {                                                \
    asm volatile("" ::: "memory");                 \
    __builtin_amdgcn_s_barrier();                  \
    asm volatile("" ::: "memory");                 \
  }

// ---------------- conversions ----------------

__global__ __launch_bounds__(256) void k_cvt_x(const float* __restrict__ x,
                                               u16* __restrict__ o) {
  int i = (blockIdx.x * 256 + threadIdx.x) * 8;
  float4 a = *(const float4*)(x + i);
  float4 b = *(const float4*)(x + i + 4);
  u16x8 r;
  r[0] = f2b(a.x); r[1] = f2b(a.y); r[2] = f2b(a.z); r[3] = f2b(a.w);
  r[4] = f2b(b.x); r[5] = f2b(b.y); r[6] = f2b(b.z); r[7] = f2b(b.w);
  *(u16x8*)(o + i) = r;
}

// W [K][N] fp32 -> Wt [N][K] bf16 (64x64 tiles via LDS).
// Wq pre-scaled by 0.125*log2(e): softmax scale fused, scores in exp2 domain.
__global__ __launch_bounds__(256) void k_cvt_wt(
    const float* __restrict__ Wq, const float* __restrict__ Wk,
    const float* __restrict__ Wv, const float* __restrict__ Wo,
    u16* __restrict__ oq, u16* __restrict__ ok, u16* __restrict__ ov,
    u16* __restrict__ oo) {
  const float* W; u16* Wt;
  int z = blockIdx.z;
  if (z == 0)      { W = Wq; Wt = oq; }
  else if (z == 1) { W = Wk; Wt = ok; }
  else if (z == 2) { W = Wv; Wt = ov; }
  else             { W = Wo; Wt = oo; }
  const float wsc = (z == 0) ? 0.1803368801111204f : 1.0f;  // 0.125*log2e
  __shared__ u16 tile[64][65];
  int k0 = blockIdx.x * 64, n0 = blockIdx.y * 64;
  int r = threadIdx.x >> 2, c0 = (threadIdx.x & 3) * 16;
  const float* src = W + (k0 + r) * DM + n0 + c0;
#pragma unroll
  for (int e = 0; e < 16; e += 4) {
    float4 v = *(const float4*)(src + e);
    tile[r][c0 + e + 0] = f2b(v.x * wsc);
    tile[r][c0 + e + 1] = f2b(v.y * wsc);
    tile[r][c0 + e + 2] = f2b(v.z * wsc);
    tile[r][c0 + e + 3] = f2b(v.w * wsc);
  }
  __syncthreads();
  u16x8 a, b;
#pragma unroll
  for (int e = 0; e < 8; ++e) a[e] = tile[c0 + e][r];
#pragma unroll
  for (int e = 0; e < 8; ++e) b[e] = tile[c0 + 8 + e][r];
  u16* dst = Wt + (n0 + r) * DM + k0 + c0;
  *(u16x8*)dst = a;
  *(u16x8*)(dst + 8) = b;
}

// ============ fused QKV GEMM: 256x256 tile, BK=64, 8 waves, phased =========
// C[4096, 3072] = X[4096,1024] * Wcat[3072,1024]^T, scattered to Q/K/V.
// LDS 128KB: 2 bufs x {A0,A1,B0,B1} halves of 16KB (128 rows x 64 cols bf16).
// XOR swizzle: LDS[rho*128 + ((chunk^(rho&7))<<4)] holds chunk of row rho,
// realized by pre-swizzled GLOBAL source + linear gll16 dest (rule 21).
// Schedule per K-tile: 4 phases, stages for Kt j+1 at phases 0-1 (into the
// other buffer), vmcnt(0) only at phase-3 end (no newer loads outstanding).

// stage one 128x64 half: src0 = ptr to (row0, kcol0); lane swizzles source.
static __device__ __forceinline__ void stage_half(const u16* src0,
                                                  char* ldsHalf, int t) {
  const int l = t & 63;
  const int ro = l >> 3;                 // row within 8-row group
  const int chunk = (l & 7) ^ ro;        // pre-swizzled source 16B-chunk
#pragma unroll
  for (int c = 0; c < 2; ++c) {
    const int g = (t >> 6) + c * 8;      // 8-row group 0..15 (wave-uniform)
    gll16(src0 + (g * 8 + ro) * DM + chunk * 8, ldsHalf + g * 1024);
  }
}

static __device__ __forceinline__ int swz(int rho, int k16) {
  return rho * 128 + (((k16) ^ (rho & 7)) << 4);
}

__global__ __launch_bounds__(512) void k_gemm_qkv_f(
    const u16* __restrict__ X, const u16* __restrict__ Wqt,
    const u16* __restrict__ Wkt, const u16* __restrict__ Wvt,
    u16* __restrict__ Qg, u16* __restrict__ Kg, u16* __restrict__ Vtg) {
  __shared__ char smem[131072];
  const int t = threadIdx.x, lane = t & 63, w = t >> 6;
  const int wm = w >> 2, wn = w & 3;     // 2 (M) x 4 (N) waves
  const int m0 = blockIdx.x * 256;
  const int by = blockIdx.y;             // 0..11
  const int z = by >> 2;                 // which of Wq/Wk/Wv
  const u16* Wt = (z == 0) ? Wqt : (z == 1) ? Wkt : Wvt;
  const u16* Bw = Wt + ((by & 3) * 256) * DM;  // this tile's 256 weight rows
  const int frow = lane & 15, fk = lane >> 4;  // frag row / k-group

  f32x4 acc[8][4];
#pragma unroll
  for (int mi = 0; mi < 8; ++mi)
#pragma unroll
    for (int ni = 0; ni < 4; ++ni) acc[mi][ni] = (f32x4){0.f, 0.f, 0.f, 0.f};

  // prologue: stage K-tile 0 into buf0, drain once
  stage_half(X + m0 * DM, smem + 0 * 16384, t);
  stage_half(X + (m0 + 128) * DM, smem + 1 * 16384, t);
  stage_half(Bw, smem + 2 * 16384, t);
  stage_half(Bw + 128 * DM, smem + 3 * 16384, t);
  asm volatile("s_waitcnt vmcnt(0)" ::: "memory");
  BARRIER();

#define MFMA16(MQ, NQ, BREG)                                                  \
  {                                                                           \
    _Pragma("unroll") for (int mi = 0; mi < 4; ++mi)                          \
        _Pragma("unroll") for (int ni = 0; ni < 2; ++ni)                      \
            _Pragma("unroll") for (int kk = 0; kk < 2; ++kk)                  \
                acc[(MQ)*4 + mi][(NQ)*2 + ni] =                               \
        __builtin_amdgcn_mfma_f32_16x16x32_bf16(                              \
            a[mi][kk], BREG[ni][kk], acc[(MQ)*4 + mi][(NQ)*2 + ni], 0, 0, 0); \
  }

  for (int j = 0; j < 16; ++j) {
    char* buf = smem + (j & 1) * 65536;
    char* nbuf = smem + ((j + 1) & 1) * 65536;
    const char* Ab = buf + wm * 16384;
    const char* Bb = buf + 2 * 16384 + (wn >> 1) * 16384;
    const int rb = (wn & 1) * 64;        // B row base within half
    const int kn = (j + 1) * 64;
    bf16x8 a[4][2], b0[2][2], b1[2][2];

    // ---- phase 0: stage A-halves(j+1); read A(mq0)+B(nq0); MFMA (0,0)
    if (j < 15) {
      stage_half(X + m0 * DM + kn, nbuf + 0 * 16384, t);
      stage_half(X + (m0 + 128) * DM + kn, nbuf + 1 * 16384, t);
    }
#pragma unroll
    for (int mi = 0; mi < 4; ++mi)
#pragma unroll
      for (int kk = 0; kk < 2; ++kk)
        a[mi][kk] = *(const bf16x8*)(Ab + swz(mi * 16 + frow, kk * 4 + fk));
#pragma unroll
    for (int ni = 0; ni < 2; ++ni)
#pragma unroll
      for (int kk = 0; kk < 2; ++kk)
        b0[ni][kk] = *(const bf16x8*)(Bb + swz(rb + ni * 16 + frow, kk * 4 + fk));
    BARRIER();
    asm volatile("s_waitcnt lgkmcnt(0)" ::: "memory");
    __builtin_amdgcn_sched_barrier(0);
    __builtin_amdgcn_s_setprio(1);
    MFMA16(0, 0, b0);
    __builtin_amdgcn_s_setprio(0);
    BARRIER();

    // ---- phase 1: stage B-halves(j+1); read B(nq1); MFMA (0,1)
    if (j < 15) {
      stage_half(Bw + kn, nbuf + 2 * 16384, t);
      stage_half(Bw + 128 * DM + kn, nbuf + 3 * 16384, t);
    }
#pragma unroll
    for (int ni = 0; ni < 2; ++ni)
#pragma unroll
      for (int kk = 0; kk < 2; ++kk)
        b1[ni][kk] =
            *(const bf16x8*)(Bb + swz(rb + 32 + ni * 16 + frow, kk * 4 + fk));
    BARRIER();
    asm volatile("s_waitcnt lgkmcnt(0)" ::: "memory");
    __builtin_amdgcn_sched_barrier(0);
    __builtin_amdgcn_s_setprio(1);
    MFMA16(0, 1, b1);
    __builtin_amdgcn_s_setprio(0);
    BARRIER();

    // ---- phase 2: read A(mq1); MFMA (1,1) reusing b1
#pragma unroll
    for (int mi = 0; mi < 4; ++mi)
#pragma unroll
      for (int kk = 0; kk < 2; ++kk)
        a[mi][kk] =
            *(const bf16x8*)(Ab + swz(64 + mi * 16 + frow, kk * 4 + fk));
    BARRIER();
    asm volatile("s_waitcnt lgkmcnt(0)" ::: "memory");
    __builtin_amdgcn_sched_barrier(0);
    __builtin_amdgcn_s_setprio(1);
    MFMA16(1, 1, b1);
    __builtin_amdgcn_s_setprio(0);
    BARRIER();

    // ---- phase 3: MFMA (1,0) reusing b0; drain stages (issued ~3 phases ago)
    __builtin_amdgcn_s_setprio(1);
    MFMA16(1, 0, b0);
    __builtin_amdgcn_s_setprio(0);
    asm volatile("s_waitcnt vmcnt(0)" ::: "memory");
    BARRIER();
  }
#undef MFMA16

  // ---- epilogue: scatter Q/K (row-major) or V (transposed) ----
  const int mW = m0 + wm * 128;
  const int nW = (by & 3) * 256 + wn * 64;   // n within this z's 1024
#pragma unroll
  for (int mi = 0; mi < 8; ++mi)
#pragma unroll
    for (int ni = 0; ni < 4; ++ni)
#pragma unroll
      for (int r = 0; r < 4; ++r) {
        int m = mW + mi * 16 + fk * 4 + r;
        int n = nW + ni * 16 + frow;
        int b = m >> 11, tt = m & 2047, h = n >> 6, d = n & 63;
        u16 val = f2b(acc[mi][ni][r]);
        if (z == 0)      Qg[((b * H_ + h) * T_ + tt) * DH + d] = val;
        else if (z == 1) Kg[((b * H_ + h) * T_ + tt) * DH + d] = val;
        else             Vtg[((b * H_ + h) * DH + d) * T_ + tt] = val;
      }
}

// ---------------- GEMM mainloop (C = A[M,K] * Bt[N,K]^T), 128x128 tile ----
// (m97 structure; still used for the output projection)

static __device__ __forceinline__ void gemm_mainloop(
    const u16* __restrict__ A, const u16* __restrict__ Bt,
    u16* As, u16* Bs, int m0, int n0, f32x4 (&acc)[4][4]) {
  const int tid = threadIdx.x;
  const int w = tid >> 6, lane = tid & 63;
  const int wr = (w >> 1) * 64, wc = (w & 1) * 64;
  for (int k0 = 0; k0 < DM; k0 += 64) {
#pragma unroll
    for (int c = 0; c < 4; ++c) {
      int row = w * 32 + c * 8 + (lane >> 3);
      int col = k0 + (lane & 7) * 8;
      gll16(A + (m0 + row) * DM + col, As + (w * 32 + c * 8) * 64);
      gll16(Bt + (n0 + row) * DM + col, Bs + (w * 32 + c * 8) * 64);
    }
    asm volatile("s_waitcnt vmcnt(0)" ::: "memory");
    __syncthreads();
#pragma unroll
    for (int kk = 0; kk < 2; ++kk) {
      bf16x8 a[4], b[4];
#pragma unroll
      for (int mi = 0; mi < 4; ++mi)
        a[mi] = *(const bf16x8*)(As + (wr + mi * 16 + (lane & 15)) * 64 +
                                 kk * 32 + (lane >> 4) * 8);
#pragma unroll
      for (int ni = 0; ni < 4; ++ni)
        b[ni] = *(const bf16x8*)(Bs + (wc + ni * 16 + (lane & 15)) * 64 +
                                 kk * 32 + (lane >> 4) * 8);
#pragma unroll
      for (int mi = 0; mi < 4; ++mi)
#pragma unroll
        for (int ni = 0; ni < 4; ++ni)
          acc[mi][ni] = __builtin_amdgcn_mfma_f32_16x16x32_bf16(
              a[mi], b[ni], acc[mi][ni], 0, 0, 0);
    }
    __syncthreads();
  }
}

// Output projection: out = Y[M,DM] * Wot^T + bo  (fp32 out)
__global__ __launch_bounds__(256) void k_gemm_out(
    const u16* __restrict__ Y, const u16* __restrict__ Wot,
    const float* __restrict__ bo, float* __restrict__ out) {
  __shared__ u16 As[128 * 64];
  __shared__ u16 Bs[128 * 64];
  const int m0 = blockIdx.x * 128, n0 = blockIdx.y * 128;
  f32x4 acc[4][4];
#pragma unroll
  for (int mi = 0; mi < 4; ++mi)
#pragma unroll
    for (int ni = 0; ni < 4; ++ni) acc[mi][ni] = (f32x4){0.f, 0.f, 0.f, 0.f};
  gemm_mainloop(Y, Wot, As, Bs, m0, n0, acc);
  const int lane = threadIdx.x & 63, w = threadIdx.x >> 6;
  const int wr = (w >> 1) * 64, wc = (w & 1) * 64;
#pragma unroll
  for (int mi = 0; mi < 4; ++mi)
#pragma unroll
    for (int ni = 0; ni < 4; ++ni)
#pragma unroll
      for (int r = 0; r < 4; ++r) {
        int m = m0 + wr + mi * 16 + (lane >> 4) * 4 + r;
        int n = n0 + wc + ni * 16 + (lane & 15);
        out[m * DM + n] = acc[mi][ni][r] + bo[n];
      }
}

// ---------------- flash attention (causal), swapped-operand 32x32 ----------
__global__ __launch_bounds__(256) void k_attn(
    const u16* __restrict__ Qg, const u16* __restrict__ Kg,
    const u16* __restrict__ Vtg, u16* __restrict__ Yg) {
  __shared__ char Kl[64 * 128];   // [j][d] bf16, swizzled
  __shared__ char Vl[64 * 128];   // [d][j] bf16, swizzled
  const int bh = blockIdx.x;
  const int qt = 15 - blockIdx.y;         // long-first (LPT) remap
  const int q0 = qt * 128;
  const int tid = threadIdx.x, w = tid >> 6, lane = tid & 63;
  const int hi = lane >> 5, qq = lane & 31;
  const u16* Qb = Qg + bh * (T_ * DH);
  const u16* Kb = Kg + bh * (T_ * DH);
  const u16* Vb = Vtg + bh * (DH * T_);
  const int qrow = q0 + w * 32 + qq;

  bf16x8 qf[4];
#pragma unroll
  for (int kb = 0; kb < 4; ++kb)
    qf[kb] = *(const bf16x8*)(Qb + qrow * DH + kb * 16 + hi * 8);

  f32x16 o0, o1;
#pragma unroll
  for (int r = 0; r < 16; ++r) { o0[r] = 0.f; o1[r] = 0.f; }
  float m = -1e30f, lp = 0.f;

  const int nt = 2 * qt + 2;
  const int nfull = 2 * qt + (w >> 1);
  const int sr = tid >> 3, sc = tid & 7;
  const int swz0 = (sr * 128 + sc * 16) ^ ((sr & 7) << 4);
  const int swz1 = ((sr + 32) * 128 + sc * 16) ^ ((sr & 7) << 4);

  u32x4 kr0 = *(const u32x4*)(Kb + sr * DH + sc * 8);
  u32x4 kr1 = *(const u32x4*)(Kb + (sr + 32) * DH + sc * 8);
  u32x4 vr0 = *(const u32x4*)(Vb + sr * T_ + sc * 8);
  u32x4 vr1 = *(const u32x4*)(Vb + (sr + 32) * T_ + sc * 8);

  for (int t = 0; t < nt; ++t) {
    __syncthreads();
    *(u32x4*)(Kl + swz0) = kr0;
    *(u32x4*)(Kl + swz1) = kr1;
    *(u32x4*)(Vl + swz0) = vr0;
    *(u32x4*)(Vl + swz1) = vr1;
    __syncthreads();
    if (t + 1 < nt) {
      const int jn = (t + 1) * 64;
      kr0 = *(const u32x4*)(Kb + (jn + sr) * DH + sc * 8);
      kr1 = *(const u32x4*)(Kb + (jn + sr + 32) * DH + sc * 8);
      vr0 = *(const u32x4*)(Vb + sr * T_ + jn + sc * 8);
      vr1 = *(const u32x4*)(Vb + (sr + 32) * T_ + jn + sc * 8);
    }
    if (t > nfull) continue;
    const int j0 = t * 64;

    f32x16 s0, s1;
#pragma unroll
    for (int r = 0; r < 16; ++r) { s0[r] = 0.f; s1[r] = 0.f; }
#pragma unroll
    for (int kb = 0; kb < 4; ++kb) {
      const int cb = (kb * 2 + hi) * 16;
      bf16x8 ka0 = *(const bf16x8*)(Kl + ((qq * 128 + cb) ^ ((qq & 7) << 4)));
      s0 = __builtin_amdgcn_mfma_f32_32x32x16_bf16(ka0, qf[kb], s0, 0, 0, 0);
      bf16x8 ka1 =
          *(const bf16x8*)(Kl + (((qq + 32) * 128 + cb) ^ ((qq & 7) << 4)));
      s1 = __builtin_amdgcn_mfma_f32_32x32x16_bf16(ka1, qf[kb], s1, 0, 0, 0);
    }
    if (t == nfull) {
#pragma unroll
      for (int r = 0; r < 16; ++r) {
        const int cr = (r & 3) + 8 * (r >> 2) + 4 * hi;
        if (j0 + cr > qrow) s0[r] = -1e30f;
        if (j0 + 32 + cr > qrow) s1[r] = -1e30f;
      }
    }
    float mt = s0[0];
#pragma unroll
    for (int r = 1; r < 16; ++r) mt = fmaxf(mt, s0[r]);
#pragma unroll
    for (int r = 0; r < 16; ++r) mt = fmaxf(mt, s1[r]);
    mt = fmaxf(mt, __shfl_xor(mt, 32));
    if (__any(mt > m + 8.f)) {
      const float mn = fmaxf(m, mt);
      const float al = __builtin_amdgcn_exp2f(m - mn);
      m = mn;
#pragma unroll
      for (int r = 0; r < 16; ++r) { o0[r] *= al; o1[r] *= al; }
      lp *= al;
    }
#pragma unroll
    for (int r = 0; r < 16; ++r) {
      s0[r] = __builtin_amdgcn_exp2f(s0[r] - m);
      s1[r] = __builtin_amdgcn_exp2f(s1[r] - m);
    }
    float ps = 0.f;
#pragma unroll
    for (int r = 0; r < 16; ++r) ps += s0[r] + s1[r];
    lp += ps;
    bf16x8 pb[4];
#define MKCH(DST, S, RB)                                                     \
  {                                                                          \
    u32 a01 = cvtpk(S[RB + 0], S[RB + 1]);                                   \
    u32 a23 = cvtpk(S[RB + 2], S[RB + 3]);                                   \
    u32 a45 = cvtpk(S[RB + 4], S[RB + 5]);                                   \
    u32 a67 = cvtpk(S[RB + 6], S[RB + 7]);                                   \
    asm volatile("v_permlane32_swap_b32 %0, %1" : "+v"(a01), "+v"(a45));     \
    asm volatile("v_permlane32_swap_b32 %0, %1" : "+v"(a23), "+v"(a67));     \
    u32x4 t4;                                                                \
    t4[0] = a01; t4[1] = a23; t4[2] = a45; t4[3] = a67;                      \
    DST = __builtin_bit_cast(bf16x8, t4);                                    \
  }
    MKCH(pb[0], s0, 0)
    MKCH(pb[1], s0, 8)
    MKCH(pb[2], s1, 0)
    MKCH(pb[3], s1, 8)
#undef MKCH
#pragma unroll
    for (int jc = 0; jc < 4; ++jc) {
      const int cb = (jc * 2 + hi) * 16;
      bf16x8 va0 = *(const bf16x8*)(Vl + ((qq * 128 + cb) ^ ((qq & 7) << 4)));
      o0 = __builtin_amdgcn_mfma_f32_32x32x16_bf16(va0, pb[jc], o0, 0, 0, 0);
      bf16x8 va1 =
          *(const bf16x8*)(Vl + (((qq + 32) * 128 + cb) ^ ((qq & 7) << 4)));
      o1 = __builtin_amdgcn_mfma_f32_32x32x16_bf16(va1, pb[jc], o1, 0, 0, 0);
    }
  }
  lp += __shfl_xor(lp, 32);
  const float rl = 1.0f / lp;
  const int obase = ((bh >> 4) * T_ + qrow) * DM + (bh & 15) * DH;
#pragma unroll
  for (int g = 0; g < 4; ++g) {
    u32x2 st;
    st[0] = cvtpk(o0[g * 4 + 0] * rl, o0[g * 4 + 1] * rl);
    st[1] = cvtpk(o0[g * 4 + 2] * rl, o0[g * 4 + 3] * rl);
    *(u32x2*)(Yg + obase + g * 8 + hi * 4) = st;
    st[0] = cvtpk(o1[g * 4 + 0] * rl, o1[g * 4 + 1] * rl);
    st[1] = cvtpk(o1[g * 4 + 2] * rl, o1[g * 4 + 3] * rl);
    *(u32x2*)(Yg + obase + 32 + g * 8 + hi * 4) = st;
  }
}

// ---------------- launch ----------------

extern "C" void kernel_launch(void* const* d_in, const int* in_sizes, int n_in,
                              void* d_out, int out_size, void* d_ws,
                              size_t ws_size, hipStream_t stream) {
  const float* x  = (const float*)d_in[0];
  const float* Wq = (const float*)d_in[1];
  const float* Wk = (const float*)d_in[2];
  const float* Wv = (const float*)d_in[3];
  const float* Wo = (const float*)d_in[4];
  const float* bo = (const float*)d_in[5];
  float* out = (float*)d_out;
  char* ws = (char*)d_ws;

  u16* xb  = (u16*)(ws);                    // 8 MiB [4096][1024]
  u16* wqt = (u16*)(ws + (8ull << 20));     // 2 MiB each, [N][K]
  u16* wkt = (u16*)(ws + (10ull << 20));
  u16* wvt = (u16*)(ws + (12ull << 20));
  u16* wot = (u16*)(ws + (14ull << 20));
  u16* Qg  = (u16*)(ws + (16ull << 20));    // 8 MiB [b,h,t,d]
  u16* Kg  = (u16*)(ws + (24ull << 20));    // 8 MiB [b,h,t,d]
  u16* Vtg = (u16*)(ws + (32ull << 20));    // 8 MiB [b,h,d,t]
  u16* Yg  = (u16*)(ws + (40ull << 20));    // 8 MiB [4096][1024]

  k_cvt_x<<<2048, 256, 0, stream>>>(x, xb);
  k_cvt_wt<<<dim3(16, 16, 4), 256, 0, stream>>>(Wq, Wk, Wv, Wo, wqt, wkt, wvt, wot);
  k_gemm_qkv_f<<<dim3(16, 12), 512, 0, stream>>>(xb, wqt, wkt, wvt, Qg, Kg, Vtg);
  k_attn<<<dim3(32, 16), 256, 0, stream>>>(Qg, Kg, Vtg, Yg);
  k_gemm_out<<<dim3(32, 8), 256, 0, stream>>>(Yg, wot, bo, out);
}

// Round 5
// 137.848 us; speedup vs baseline: 1.3314x; 1.0087x over previous
//
#include <hip/hip_runtime.h>

#define T_   2048
#define DM   1024
#define H_   16
#define DH   64

typedef unsigned short u16;
typedef unsigned int u32;
typedef __attribute__((ext_vector_type(8))) short bf16x8;   // 8 bf16 = 4 VGPR
typedef __attribute__((ext_vector_type(8))) unsigned short u16x8;
typedef __attribute__((ext_vector_type(4))) float f32x4;
typedef __attribute__((ext_vector_type(16))) float f32x16;
typedef __attribute__((ext_vector_type(4))) unsigned int u32x4;
typedef __attribute__((ext_vector_type(2))) unsigned int u32x2;

static __device__ __forceinline__ u16 f2b(float f) {
  unsigned int u = __builtin_bit_cast(unsigned int, f);
  u += 0x7fff + ((u >> 16) & 1);   // RNE
  return (u16)(u >> 16);
}

static __device__ __forceinline__ u32 cvtpk(float a, float b) {
  u32 d;
  asm("v_cvt_pk_bf16_f32 %0, %1, %2" : "=v"(d) : "v"(a), "v"(b));
  return d;   // lo = bf16(a), hi = bf16(b)
}

static __device__ __forceinline__ void gll16(const void* g, void* l) {
  __builtin_amdgcn_global_load_lds(
      (const __attribute__((address_space(1))) unsigned int*)g,
      (__attribute__((address_space(3))) unsigned int*)l, 16, 0, 0);
}

#define BARRIER()                                  \
  {                                                \
    asm volatile("" ::: "memory");                 \
    __builtin_amdgcn_s_barrier();                  \
    asm volatile("" ::: "memory");                 \
  }

// ---------------- conversions ----------------

__global__ __launch_bounds__(256) void k_cvt_x(const float* __restrict__ x,
                                               u16* __restrict__ o) {
  int i = (blockIdx.x * 256 + threadIdx.x) * 8;
  float4 a = *(const float4*)(x + i);
  float4 b = *(const float4*)(x + i + 4);
  u16x8 r;
  r[0] = f2b(a.x); r[1] = f2b(a.y); r[2] = f2b(a.z); r[3] = f2b(a.w);
  r[4] = f2b(b.x); r[5] = f2b(b.y); r[6] = f2b(b.z); r[7] = f2b(b.w);
  *(u16x8*)(o + i) = r;
}

// W [K][N] fp32 -> Wt [N][K] bf16 (64x64 tiles via LDS).
// Wq pre-scaled by 0.125*log2(e): softmax scale fused, scores in exp2 domain.
__global__ __launch_bounds__(256) void k_cvt_wt(
    const float* __restrict__ Wq, const float* __restrict__ Wk,
    const float* __restrict__ Wv, const float* __restrict__ Wo,
    u16* __restrict__ oq, u16* __restrict__ ok, u16* __restrict__ ov,
    u16* __restrict__ oo) {
  const float* W; u16* Wt;
  int z = blockIdx.z;
  if (z == 0)      { W = Wq; Wt = oq; }
  else if (z == 1) { W = Wk; Wt = ok; }
  else if (z == 2) { W = Wv; Wt = ov; }
  else             { W = Wo; Wt = oo; }
  const float wsc = (z == 0) ? 0.1803368801111204f : 1.0f;  // 0.125*log2e
  __shared__ u16 tile[64][65];
  int k0 = blockIdx.x * 64, n0 = blockIdx.y * 64;
  int r = threadIdx.x >> 2, c0 = (threadIdx.x & 3) * 16;
  const float* src = W + (k0 + r) * DM + n0 + c0;
#pragma unroll
  for (int e = 0; e < 16; e += 4) {
    float4 v = *(const float4*)(src + e);
    tile[r][c0 + e + 0] = f2b(v.x * wsc);
    tile[r][c0 + e + 1] = f2b(v.y * wsc);
    tile[r][c0 + e + 2] = f2b(v.z * wsc);
    tile[r][c0 + e + 3] = f2b(v.w * wsc);
  }
  __syncthreads();
  u16x8 a, b;
#pragma unroll
  for (int e = 0; e < 8; ++e) a[e] = tile[c0 + e][r];
#pragma unroll
  for (int e = 0; e < 8; ++e) b[e] = tile[c0 + 8 + e][r];
  u16* dst = Wt + (n0 + r) * DM + k0 + c0;
  *(u16x8*)dst = a;
  *(u16x8*)(dst + 8) = b;
}

// ============ fused QKV GEMM: 256x256 tile, BK=64, 8 waves ==================
// Quadrant phases + JIT unit staging + COUNTED vmcnt (T3+T4, never drain-0).
// LDS 128KB: 2 bufs x {A[256][64], B[256][64]} bf16, XOR-swizzled
// (slot = chunk ^ (row&7), realized by pre-swizzled global source — rule 21).
// Per K-tile j, phases = C-quadrants (0,0),(0,1),(1,1),(1,0); LDS data needed
// incrementally: {A-lo,B-even}@ph0, B-odd@ph1, A-hi@ph2, none@ph3.
// Stages during tile j (deadline-matched, 2 gll16/thread each):
//   ph0: A-lo(j+1)  ph1: B-even(j+1)  ph2: B-odd(j+1)  ph3: A-hi(j+1)
// Waits: vmcnt(4) at end of ph0/ph1/ph3, none at ph2 (tail j=15: 2/0).

static __device__ __forceinline__ void stage2(const u16* src, char* lds,
                                              int rho0, int rho1, int ro,
                                              int ce) {
  gll16(src + (rho0 + ro) * DM + ce, lds + rho0 * 128);
  gll16(src + (rho1 + ro) * DM + ce, lds + rho1 * 128);
}

static __device__ __forceinline__ bf16x8 ldf(const char* base, int rho,
                                             int k16) {
  return *(const bf16x8*)(base + rho * 128 + ((k16 ^ (rho & 7)) << 4));
}

__global__ __launch_bounds__(512) void k_gemm_qkv_f(
    const u16* __restrict__ X, const u16* __restrict__ Wqt,
    const u16* __restrict__ Wkt, const u16* __restrict__ Wvt,
    u16* __restrict__ Qg, u16* __restrict__ Kg, u16* __restrict__ Vtg) {
  __shared__ char smem[131072];
  const int t = threadIdx.x, lane = t & 63, w = t >> 6;
  const int wm = w >> 2, wn = w & 3;     // 2 (M) x 4 (N) waves
  const int m0 = blockIdx.x * 256;
  const int by = blockIdx.y;             // 0..11
  const int z = by >> 2;                 // which of Wq/Wk/Wv
  const u16* Wt = (z == 0) ? Wqt : (z == 1) ? Wkt : Wvt;
  const u16* Bw = Wt + ((by & 3) * 256) * DM;  // this tile's 256 weight rows
  const u16* Xr = X + m0 * DM;
  const int frow = lane & 15, fk = lane >> 4;  // frag row / k-group

  // staging lane geometry
  const int ro = lane >> 3;              // row within 8-row group
  const int ce = (((lane & 7) ^ ro) << 3);  // pre-swizzled chunk, elem offset
  const int alo0 = w * 8;                // A-lo rho (c=0); c=1 is +128
  const int ahi0 = 64 + w * 8;
  const int bev0 = (w >> 2) * 64 + (w & 3) * 8;
  const int bod0 = bev0 + 32;

  f32x4 acc[8][4];
#pragma unroll
  for (int mi = 0; mi < 8; ++mi)
#pragma unroll
    for (int ni = 0; ni < 4; ++ni) acc[mi][ni] = (f32x4){0.f, 0.f, 0.f, 0.f};

  // prologue: tile 0 into buf0, deadline order; counted drain (keep 2 units)
  stage2(Xr, smem, alo0, alo0 + 128, ro, ce);
  stage2(Bw, smem + 32768, bev0, bev0 + 128, ro, ce);
  stage2(Bw, smem + 32768, bod0, bod0 + 128, ro, ce);
  stage2(Xr, smem, ahi0, ahi0 + 128, ro, ce);
  asm volatile("s_waitcnt vmcnt(4)" ::: "memory");
  BARRIER();

#define MFMA16(MQ, NQ, BREG)                                                  \
  {                                                                           \
    _Pragma("unroll") for (int mi = 0; mi < 4; ++mi)                          \
        _Pragma("unroll") for (int ni = 0; ni < 2; ++ni)                      \
            _Pragma("unroll") for (int kk = 0; kk < 2; ++kk)                  \
                acc[(MQ)*4 + mi][(NQ)*2 + ni] =                               \
        __builtin_amdgcn_mfma_f32_16x16x32_bf16(                              \
            a[mi][kk], BREG[ni][kk], acc[(MQ)*4 + mi][(NQ)*2 + ni], 0, 0, 0); \
  }
#define LGKM0()                                          \
  asm volatile("s_waitcnt lgkmcnt(0)" ::: "memory");     \
  __builtin_amdgcn_sched_barrier(0);

  for (int j = 0; j < 16; ++j) {
    char* buf = smem + (j & 1) * 65536;
    char* nA = smem + ((j + 1) & 1) * 65536;
    char* nB = nA + 32768;
    const char* Ab = buf;
    const char* Bb = buf + 32768;
    const u16* XA = Xr + (j + 1) * 64;
    const u16* BW = Bw + (j + 1) * 64;
    const bool st = (j < 15);
    bf16x8 a[4][2], b0[2][2], b1[2][2];

    // ---- phase 0: read A(mq0)+B(nq0); stage A-lo(j+1); MFMA (0,0)
#pragma unroll
    for (int mi = 0; mi < 4; ++mi)
#pragma unroll
      for (int kk = 0; kk < 2; ++kk)
        a[mi][kk] = ldf(Ab, wm * 128 + mi * 16 + frow, kk * 4 + fk);
#pragma unroll
    for (int ni = 0; ni < 2; ++ni)
#pragma unroll
      for (int kk = 0; kk < 2; ++kk)
        b0[ni][kk] = ldf(Bb, wn * 64 + ni * 16 + frow, kk * 4 + fk);
    if (st) stage2(XA, nA, alo0, alo0 + 128, ro, ce);
    BARRIER();
    LGKM0();
    __builtin_amdgcn_s_setprio(1);
    MFMA16(0, 0, b0);
    __builtin_amdgcn_s_setprio(0);
    if (st) { asm volatile("s_waitcnt vmcnt(4)" ::: "memory"); }
    else    { asm volatile("s_waitcnt vmcnt(2)" ::: "memory"); }
    BARRIER();

    // ---- phase 1: read B(nq1); stage B-even(j+1); MFMA (0,1)
#pragma unroll
    for (int ni = 0; ni < 2; ++ni)
#pragma unroll
      for (int kk = 0; kk < 2; ++kk)
        b1[ni][kk] = ldf(Bb, wn * 64 + 32 + ni * 16 + frow, kk * 4 + fk);
    if (st) stage2(BW, nB, bev0, bev0 + 128, ro, ce);
    BARRIER();
    LGKM0();
    __builtin_amdgcn_s_setprio(1);
    MFMA16(0, 1, b1);
    __builtin_amdgcn_s_setprio(0);
    if (st) { asm volatile("s_waitcnt vmcnt(4)" ::: "memory"); }
    else    { asm volatile("s_waitcnt vmcnt(0)" ::: "memory"); }
    BARRIER();

    // ---- phase 2: read A(mq1); stage B-odd(j+1); MFMA (1,1)
#pragma unroll
    for (int mi = 0; mi < 4; ++mi)
#pragma unroll
      for (int kk = 0; kk < 2; ++kk)
        a[mi][kk] = ldf(Ab, wm * 128 + 64 + mi * 16 + frow, kk * 4 + fk);
    if (st) stage2(BW, nB, bod0, bod0 + 128, ro, ce);
    BARRIER();
    LGKM0();
    __builtin_amdgcn_s_setprio(1);
    MFMA16(1, 1, b1);
    __builtin_amdgcn_s_setprio(0);
    BARRIER();                                // no vmcnt: ph3 reads nothing

    // ---- phase 3: stage A-hi(j+1); MFMA (1,0) reusing b0
    if (st) stage2(XA, nA, ahi0, ahi0 + 128, ro, ce);
    __builtin_amdgcn_s_setprio(1);
    MFMA16(1, 0, b0);
    __builtin_amdgcn_s_setprio(0);
    if (st) { asm volatile("s_waitcnt vmcnt(4)" ::: "memory"); }
    BARRIER();
  }
#undef MFMA16
#undef LGKM0

  // ---- epilogue: scatter Q/K (row-major) or V (transposed) ----
  const int mW = m0 + wm * 128;
  const int nW = (by & 3) * 256 + wn * 64;   // n within this z's 1024
#pragma unroll
  for (int mi = 0; mi < 8; ++mi)
#pragma unroll
    for (int ni = 0; ni < 4; ++ni)
#pragma unroll
      for (int r = 0; r < 4; ++r) {
        int m = mW + mi * 16 + fk * 4 + r;
        int n = nW + ni * 16 + frow;
        int b = m >> 11, tt = m & 2047, h = n >> 6, d = n & 63;
        u16 val = f2b(acc[mi][ni][r]);
        if (z == 0)      Qg[((b * H_ + h) * T_ + tt) * DH + d] = val;
        else if (z == 1) Kg[((b * H_ + h) * T_ + tt) * DH + d] = val;
        else             Vtg[((b * H_ + h) * DH + d) * T_ + tt] = val;
      }
}

// ---------------- GEMM mainloop (C = A[M,K] * Bt[N,K]^T), 128x128 tile ----
// (m97 structure; still used for the output projection)

static __device__ __forceinline__ void gemm_mainloop(
    const u16* __restrict__ A, const u16* __restrict__ Bt,
    u16* As, u16* Bs, int m0, int n0, f32x4 (&acc)[4][4]) {
  const int tid = threadIdx.x;
  const int w = tid >> 6, lane = tid & 63;
  const int wr = (w >> 1) * 64, wc = (w & 1) * 64;
  for (int k0 = 0; k0 < DM; k0 += 64) {
#pragma unroll
    for (int c = 0; c < 4; ++c) {
      int row = w * 32 + c * 8 + (lane >> 3);
      int col = k0 + (lane & 7) * 8;
      gll16(A + (m0 + row) * DM + col, As + (w * 32 + c * 8) * 64);
      gll16(Bt + (n0 + row) * DM + col, Bs + (w * 32 + c * 8) * 64);
    }
    asm volatile("s_waitcnt vmcnt(0)" ::: "memory");
    __syncthreads();
#pragma unroll
    for (int kk = 0; kk < 2; ++kk) {
      bf16x8 a[4], b[4];
#pragma unroll
      for (int mi = 0; mi < 4; ++mi)
        a[mi] = *(const bf16x8*)(As + (wr + mi * 16 + (lane & 15)) * 64 +
                                 kk * 32 + (lane >> 4) * 8);
#pragma unroll
      for (int ni = 0; ni < 4; ++ni)
        b[ni] = *(const bf16x8*)(Bs + (wc + ni * 16 + (lane & 15)) * 64 +
                                 kk * 32 + (lane >> 4) * 8);
#pragma unroll
      for (int mi = 0; mi < 4; ++mi)
#pragma unroll
        for (int ni = 0; ni < 4; ++ni)
          acc[mi][ni] = __builtin_amdgcn_mfma_f32_16x16x32_bf16(
              a[mi], b[ni], acc[mi][ni], 0, 0, 0);
    }
    __syncthreads();
  }
}

// Output projection: out = Y[M,DM] * Wot^T + bo  (fp32 out)
__global__ __launch_bounds__(256) void k_gemm_out(
    const u16* __restrict__ Y, const u16* __restrict__ Wot,
    const float* __restrict__ bo, float* __restrict__ out) {
  __shared__ u16 As[128 * 64];
  __shared__ u16 Bs[128 * 64];
  const int m0 = blockIdx.x * 128, n0 = blockIdx.y * 128;
  f32x4 acc[4][4];
#pragma unroll
  for (int mi = 0; mi < 4; ++mi)
#pragma unroll
    for (int ni = 0; ni < 4; ++ni) acc[mi][ni] = (f32x4){0.f, 0.f, 0.f, 0.f};
  gemm_mainloop(Y, Wot, As, Bs, m0, n0, acc);
  const int lane = threadIdx.x & 63, w = threadIdx.x >> 6;
  const int wr = (w >> 1) * 64, wc = (w & 1) * 64;
#pragma unroll
  for (int mi = 0; mi < 4; ++mi)
#pragma unroll
    for (int ni = 0; ni < 4; ++ni)
#pragma unroll
      for (int r = 0; r < 4; ++r) {
        int m = m0 + wr + mi * 16 + (lane >> 4) * 4 + r;
        int n = n0 + wc + ni * 16 + (lane & 15);
        out[m * DM + n] = acc[mi][ni][r] + bo[n];
      }
}

// ---------------- flash attention (causal), swapped-operand 32x32 ----------
__global__ __launch_bounds__(256) void k_attn(
    const u16* __restrict__ Qg, const u16* __restrict__ Kg,
    const u16* __restrict__ Vtg, u16* __restrict__ Yg) {
  __shared__ char Kl[64 * 128];   // [j][d] bf16, swizzled
  __shared__ char Vl[64 * 128];   // [d][j] bf16, swizzled
  const int bh = blockIdx.x;
  const int qt = 15 - blockIdx.y;         // long-first (LPT) remap
  const int q0 = qt * 128;
  const int tid = threadIdx.x, w = tid >> 6, lane = tid & 63;
  const int hi = lane >> 5, qq = lane & 31;
  const u16* Qb = Qg + bh * (T_ * DH);
  const u16* Kb = Kg + bh * (T_ * DH);
  const u16* Vb = Vtg + bh * (DH * T_);
  const int qrow = q0 + w * 32 + qq;

  bf16x8 qf[4];
#pragma unroll
  for (int kb = 0; kb < 4; ++kb)
    qf[kb] = *(const bf16x8*)(Qb + qrow * DH + kb * 16 + hi * 8);

  f32x16 o0, o1;
#pragma unroll
  for (int r = 0; r < 16; ++r) { o0[r] = 0.f; o1[r] = 0.f; }
  float m = -1e30f, lp = 0.f;

  const int nt = 2 * qt + 2;
  const int nfull = 2 * qt + (w >> 1);
  const int sr = tid >> 3, sc = tid & 7;
  const int swz0 = (sr * 128 + sc * 16) ^ ((sr & 7) << 4);
  const int swz1 = ((sr + 32) * 128 + sc * 16) ^ ((sr & 7) << 4);

  u32x4 kr0 = *(const u32x4*)(Kb + sr * DH + sc * 8);
  u32x4 kr1 = *(const u32x4*)(Kb + (sr + 32) * DH + sc * 8);
  u32x4 vr0 = *(const u32x4*)(Vb + sr * T_ + sc * 8);
  u32x4 vr1 = *(const u32x4*)(Vb + (sr + 32) * T_ + sc * 8);

  for (int t = 0; t < nt; ++t) {
    __syncthreads();
    *(u32x4*)(Kl + swz0) = kr0;
    *(u32x4*)(Kl + swz1) = kr1;
    *(u32x4*)(Vl + swz0) = vr0;
    *(u32x4*)(Vl + swz1) = vr1;
    __syncthreads();
    if (t + 1 < nt) {
      const int jn = (t + 1) * 64;
      kr0 = *(const u32x4*)(Kb + (jn + sr) * DH + sc * 8);
      kr1 = *(const u32x4*)(Kb + (jn + sr + 32) * DH + sc * 8);
      vr0 = *(const u32x4*)(Vb + sr * T_ + jn + sc * 8);
      vr1 = *(const u32x4*)(Vb + (sr + 32) * T_ + jn + sc * 8);
    }
    if (t > nfull) continue;
    const int j0 = t * 64;

    f32x16 s0, s1;
#pragma unroll
    for (int r = 0; r < 16; ++r) { s0[r] = 0.f; s1[r] = 0.f; }
#pragma unroll
    for (int kb = 0; kb < 4; ++kb) {
      const int cb = (kb * 2 + hi) * 16;
      bf16x8 ka0 = *(const bf16x8*)(Kl + ((qq * 128 + cb) ^ ((qq & 7) << 4)));
      s0 = __builtin_amdgcn_mfma_f32_32x32x16_bf16(ka0, qf[kb], s0, 0, 0, 0);
      bf16x8 ka1 =
          *(const bf16x8*)(Kl + (((qq + 32) * 128 + cb) ^ ((qq & 7) << 4)));
      s1 = __builtin_amdgcn_mfma_f32_32x32x16_bf16(ka1, qf[kb], s1, 0, 0, 0);
    }
    if (t == nfull) {
#pragma unroll
      for (int r = 0; r < 16; ++r) {
        const int cr = (r & 3) + 8 * (r >> 2) + 4 * hi;
        if (j0 + cr > qrow) s0[r] = -1e30f;
        if (j0 + 32 + cr > qrow) s1[r] = -1e30f;
      }
    }
    float mt = s0[0];
#pragma unroll
    for (int r = 1; r < 16; ++r) mt = fmaxf(mt, s0[r]);
#pragma unroll
    for (int r = 0; r < 16; ++r) mt = fmaxf(mt, s1[r]);
    mt = fmaxf(mt, __shfl_xor(mt, 32));
    if (__any(mt > m + 8.f)) {
      const float mn = fmaxf(m, mt);
      const float al = __builtin_amdgcn_exp2f(m - mn);
      m = mn;
#pragma unroll
      for (int r = 0; r < 16; ++r) { o0[r] *= al; o1[r] *= al; }
      lp *= al;
    }
#pragma unroll
    for (int r = 0; r < 16; ++r) {
      s0[r] = __builtin_amdgcn_exp2f(s0[r] - m);
      s1[r] = __builtin_amdgcn_exp2f(s1[r] - m);
    }
    float ps = 0.f;
#pragma unroll
    for (int r = 0; r < 16; ++r) ps += s0[r] + s1[r];
    lp += ps;
    bf16x8 pb[4];
#define MKCH(DST, S, RB)                                                     \
  {                                                                          \
    u32 a01 = cvtpk(S[RB + 0], S[RB + 1]);                                   \
    u32 a23 = cvtpk(S[RB + 2], S[RB + 3]);                                   \
    u32 a45 = cvtpk(S[RB + 4], S[RB + 5]);                                   \
    u32 a67 = cvtpk(S[RB + 6], S[RB + 7]);                                   \
    asm volatile("v_permlane32_swap_b32 %0, %1" : "+v"(a01), "+v"(a45));     \
    asm volatile("v_permlane32_swap_b32 %0, %1" : "+v"(a23), "+v"(a67));     \
    u32x4 t4;                                                                \
    t4[0] = a01; t4[1] = a23; t4[2] = a45; t4[3] = a67;                      \
    DST = __builtin_bit_cast(bf16x8, t4);                                    \
  }
    MKCH(pb[0], s0, 0)
    MKCH(pb[1], s0, 8)
    MKCH(pb[2], s1, 0)
    MKCH(pb[3], s1, 8)
#undef MKCH
#pragma unroll
    for (int jc = 0; jc < 4; ++jc) {
      const int cb = (jc * 2 + hi) * 16;
      bf16x8 va0 = *(const bf16x8*)(Vl + ((qq * 128 + cb) ^ ((qq & 7) << 4)));
      o0 = __builtin_amdgcn_mfma_f32_32x32x16_bf16(va0, pb[jc], o0, 0, 0, 0);
      bf16x8 va1 =
          *(const bf16x8*)(Vl + (((qq + 32) * 128 + cb) ^ ((qq & 7) << 4)));
      o1 = __builtin_amdgcn_mfma_f32_32x32x16_bf16(va1, pb[jc], o1, 0, 0, 0);
    }
  }
  lp += __shfl_xor(lp, 32);
  const float rl = 1.0f / lp;
  const int obase = ((bh >> 4) * T_ + qrow) * DM + (bh & 15) * DH;
#pragma unroll
  for (int g = 0; g < 4; ++g) {
    u32x2 st;
    st[0] = cvtpk(o0[g * 4 + 0] * rl, o0[g * 4 + 1] * rl);
    st[1] = cvtpk(o0[g * 4 + 2] * rl, o0[g * 4 + 3] * rl);
    *(u32x2*)(Yg + obase + g * 8 + hi * 4) = st;
    st[0] = cvtpk(o1[g * 4 + 0] * rl, o1[g * 4 + 1] * rl);
    st[1] = cvtpk(o1[g * 4 + 2] * rl, o1[g * 4 + 3] * rl);
    *(u32x2*)(Yg + obase + 32 + g * 8 + hi * 4) = st;
  }
}

// ---------------- launch ----------------

extern "C" void kernel_launch(void* const* d_in, const int* in_sizes, int n_in,
                              void* d_out, int out_size, void* d_ws,
                              size_t ws_size, hipStream_t stream) {
  const float* x  = (const float*)d_in[0];
  const float* Wq = (const float*)d_in[1];
  const float* Wk = (const float*)d_in[2];
  const float* Wv = (const float*)d_in[3];
  const float* Wo = (const float*)d_in[4];
  const float* bo = (const float*)d_in[5];
  float* out = (float*)d_out;
  char* ws = (char*)d_ws;

  u16* xb  = (u16*)(ws);                    // 8 MiB [4096][1024]
  u16* wqt = (u16*)(ws + (8ull << 20));     // 2 MiB each, [N][K]
  u16* wkt = (u16*)(ws + (10ull << 20));
  u16* wvt = (u16*)(ws + (12ull << 20));
  u16* wot = (u16*)(ws + (14ull << 20));
  u16* Qg  = (u16*)(ws + (16ull << 20));    // 8 MiB [b,h,t,d]
  u16* Kg  = (u16*)(ws + (24ull << 20));    // 8 MiB [b,h,t,d]
  u16* Vtg = (u16*)(ws + (32ull << 20));    // 8 MiB [b,h,d,t]
  u16* Yg  = (u16*)(ws + (40ull << 20));    // 8 MiB [4096][1024]

  k_cvt_x<<<2048, 256, 0, stream>>>(x, xb);
  k_cvt_wt<<<dim3(16, 16, 4), 256, 0, stream>>>(Wq, Wk, Wv, Wo, wqt, wkt, wvt, wot);
  k_gemm_qkv_f<<<dim3(16, 12), 512, 0, stream>>>(xb, wqt, wkt, wvt, Qg, Kg, Vtg);
  k_attn<<<dim3(32, 16), 256, 0, stream>>>(Qg, Kg, Vtg, Yg);
  k_gemm_out<<<dim3(32, 8), 256, 0, stream>>>(Yg, wot, bo, out);
}

// Round 7
// 118.279 us; speedup vs baseline: 1.5517x; 1.1654x over previous
//
#include <hip/hip_runtime.h>

#define T_   2048
#define DM   1024
#define H_   16
#define DH   64

typedef unsigned short u16;
typedef unsigned int u32;
typedef __attribute__((ext_vector_type(8))) short bf16x8;   // 8 bf16 = 4 VGPR
typedef __attribute__((ext_vector_type(8))) unsigned short u16x8;
typedef __attribute__((ext_vector_type(4))) float f32x4;
typedef __attribute__((ext_vector_type(16))) float f32x16;
typedef __attribute__((ext_vector_type(4))) unsigned int u32x4;
typedef __attribute__((ext_vector_type(2))) unsigned int u32x2;

static __device__ __forceinline__ u16 f2b(float f) {
  unsigned int u = __builtin_bit_cast(unsigned int, f);
  u += 0x7fff + ((u >> 16) & 1);   // RNE
  return (u16)(u >> 16);
}

static __device__ __forceinline__ u32 cvtpk(float a, float b) {
  u32 d;
  asm("v_cvt_pk_bf16_f32 %0, %1, %2" : "=v"(d) : "v"(a), "v"(b));
  return d;   // lo = bf16(a), hi = bf16(b)
}

static __device__ __forceinline__ void gll16(const void* g, void* l) {
  __builtin_amdgcn_global_load_lds(
      (const __attribute__((address_space(1))) unsigned int*)g,
      (__attribute__((address_space(3))) unsigned int*)l, 16, 0, 0);
}

// swizzled LDS fragment read: row stride 128B, 16B chunk XOR'd by row&7.
// Matching stage: linear gll16 dest + pre-swizzled global source (rule 21).
static __device__ __forceinline__ bf16x8 ldf(const char* base, int rho,
                                             int k16) {
  return *(const bf16x8*)(base + rho * 128 + ((k16 ^ (rho & 7)) << 4));
}

// ---------------- conversions ----------------

__global__ __launch_bounds__(256) void k_cvt_x(const float* __restrict__ x,
                                               u16* __restrict__ o) {
  int i = (blockIdx.x * 256 + threadIdx.x) * 8;
  float4 a = *(const float4*)(x + i);
  float4 b = *(const float4*)(x + i + 4);
  u16x8 r;
  r[0] = f2b(a.x); r[1] = f2b(a.y); r[2] = f2b(a.z); r[3] = f2b(a.w);
  r[4] = f2b(b.x); r[5] = f2b(b.y); r[6] = f2b(b.z); r[7] = f2b(b.w);
  *(u16x8*)(o + i) = r;
}

// W [K][N] fp32 -> Wt [N][K] bf16 (64x64 tiles via LDS).
// Wq pre-scaled by 0.125*log2(e): softmax scale fused, scores in exp2 domain.
__global__ __launch_bounds__(256) void k_cvt_wt(
    const float* __restrict__ Wq, const float* __restrict__ Wk,
    const float* __restrict__ Wv, const float* __restrict__ Wo,
    u16* __restrict__ oq, u16* __restrict__ ok, u16* __restrict__ ov,
    u16* __restrict__ oo) {
  const float* W; u16* Wt;
  int z = blockIdx.z;
  if (z == 0)      { W = Wq; Wt = oq; }
  else if (z == 1) { W = Wk; Wt = ok; }
  else if (z == 2) { W = Wv; Wt = ov; }
  else             { W = Wo; Wt = oo; }
  const float wsc = (z == 0) ? 0.1803368801111204f : 1.0f;  // 0.125*log2e
  __shared__ u16 tile[64][65];
  int k0 = blockIdx.x * 64, n0 = blockIdx.y * 64;
  int r = threadIdx.x >> 2, c0 = (threadIdx.x & 3) * 16;
  const float* src = W + (k0 + r) * DM + n0 + c0;
#pragma unroll
  for (int e = 0; e < 16; e += 4) {
    float4 v = *(const float4*)(src + e);
    tile[r][c0 + e + 0] = f2b(v.x * wsc);
    tile[r][c0 + e + 1] = f2b(v.y * wsc);
    tile[r][c0 + e + 2] = f2b(v.z * wsc);
    tile[r][c0 + e + 3] = f2b(v.w * wsc);
  }
  __syncthreads();
  u16x8 a, b;
#pragma unroll
  for (int e = 0; e < 8; ++e) a[e] = tile[c0 + e][r];
#pragma unroll
  for (int e = 0; e < 8; ++e) b[e] = tile[c0 + 8 + e][r];
  u16* dst = Wt + (n0 + r) * DM + k0 + c0;
  *(u16x8*)dst = a;
  *(u16x8*)(dst + 8) = b;
}

// ============ QKV GEMM: m97 regime — 128x128 tile, 4 waves, 3 blocks/CU ====
// grid (32, 24): by>>3 = z (Q/K/V), by&7 = n-tile.  BK=64, single-buffer
// 32KB LDS, gll16 width-16 staging, drain vmcnt(0)+__syncthreads per K-step
// (cross-block TLP fills the drain at 3 blocks/CU — m97/m114).  XOR-swizzled
// LDS (conflicts ~0).  V epilogue: LDS-bounce transpose -> coalesced stores.
__global__ __launch_bounds__(256) void k_qkv(
    const u16* __restrict__ X, const u16* __restrict__ Wqt,
    const u16* __restrict__ Wkt, const u16* __restrict__ Wvt,
    u16* __restrict__ Qg, u16* __restrict__ Kg, u16* __restrict__ Vtg) {
  __shared__ char smem[34816];           // staging 32KB | V-transpose 34KB
  char* As = smem;                       // [128][64] bf16, swizzled
  char* Bs = smem + 16384;
  const int tid = threadIdx.x, lane = tid & 63, w = tid >> 6;
  const int frow = lane & 15, fk = lane >> 4;
  const int wr = (w >> 1) * 64, wc = (w & 1) * 64;
  const int m0 = blockIdx.x * 128;
  const int by = blockIdx.y;
  const int z = by >> 3, n0 = (by & 7) * 128;
  const u16* Wt = (z == 0) ? Wqt : (z == 1) ? Wkt : Wvt;
  const u16* Ap = X + m0 * DM;
  const u16* Bp = Wt + n0 * DM;
  const int ro = lane >> 3;
  const int ce = ((lane & 7) ^ ro) << 3;   // pre-swizzled source chunk (elems)

  f32x4 acc[4][4];
#pragma unroll
  for (int mi = 0; mi < 4; ++mi)
#pragma unroll
    for (int ni = 0; ni < 4; ++ni) acc[mi][ni] = (f32x4){0.f, 0.f, 0.f, 0.f};

  for (int k0 = 0; k0 < DM; k0 += 64) {
#pragma unroll
    for (int c = 0; c < 4; ++c) {
      const int g8 = (w * 4 + c) * 8;      // 8-row group base
      gll16(Ap + (g8 + ro) * DM + k0 + ce, As + g8 * 128);
      gll16(Bp + (g8 + ro) * DM + k0 + ce, Bs + g8 * 128);
    }
    asm volatile("s_waitcnt vmcnt(0)" ::: "memory");
    __syncthreads();
    bf16x8 a[4][2], b[4][2];
#pragma unroll
    for (int mi = 0; mi < 4; ++mi)
#pragma unroll
      for (int kk = 0; kk < 2; ++kk)
        a[mi][kk] = ldf(As, wr + mi * 16 + frow, kk * 4 + fk);
#pragma unroll
    for (int ni = 0; ni < 4; ++ni)
#pragma unroll
      for (int kk = 0; kk < 2; ++kk)
        b[ni][kk] = ldf(Bs, wc + ni * 16 + frow, kk * 4 + fk);
#pragma unroll
    for (int mi = 0; mi < 4; ++mi)
#pragma unroll
      for (int ni = 0; ni < 4; ++ni)
#pragma unroll
        for (int kk = 0; kk < 2; ++kk)
          acc[mi][ni] = __builtin_amdgcn_mfma_f32_16x16x32_bf16(
              a[mi][kk], b[ni][kk], acc[mi][ni], 0, 0, 0);
    __syncthreads();
  }

  if (z < 2) {
    // Q/K: direct scatter (16-lane 32B runs along d)
    u16* out = (z == 0) ? Qg : Kg;
#pragma unroll
    for (int mi = 0; mi < 4; ++mi)
#pragma unroll
      for (int ni = 0; ni < 4; ++ni)
#pragma unroll
        for (int r = 0; r < 4; ++r) {
          int m = m0 + wr + mi * 16 + fk * 4 + r;
          int nl = n0 + wc + ni * 16 + frow;
          int b = m >> 11, t = m & 2047, h = nl >> 6, d = nl & 63;
          out[((b * H_ + h) * T_ + t) * DH + d] = f2b(acc[mi][ni][r]);
        }
  } else {
    // V: LDS-bounce transpose -> coalesced 16B stores along t
    u16* Tl = (u16*)smem;                // [128][136]
#pragma unroll
    for (int ni = 0; ni < 4; ++ni) {
      const int n = wc + ni * 16 + frow;
#pragma unroll
      for (int mi = 0; mi < 4; ++mi)
#pragma unroll
        for (int r = 0; r < 4; ++r)
          Tl[n * 136 + wr + mi * 16 + fk * 4 + r] = f2b(acc[mi][ni][r]);
    }
    __syncthreads();
    const int n = tid >> 1, c0 = (tid & 1) * 64;
    const int ng = n0 + n, h = ng >> 6, d = ng & 63;
    const int b = m0 >> 11;
    const int tb = (m0 & 2047) + c0;     // in-batch t base (BUGFIX: & 2047)
    u16* dst = Vtg + ((b * H_ + h) * DH + d) * T_ + tb;
#pragma unroll
    for (int e = 0; e < 8; ++e)
      *(u16x8*)(dst + e * 8) = *(const u16x8*)(Tl + n * 136 + c0 + e * 8);
  }
}

// ============ output projection: 64x128 tile, 4 waves, 2 blocks/CU =========
// out[4096,1024] = Y[4096,1024] * Wot[1024,1024]^T + bo, fp32 out.
__global__ __launch_bounds__(256) void k_out(
    const u16* __restrict__ Y, const u16* __restrict__ Wot,
    const float* __restrict__ bo, float* __restrict__ out) {
  __shared__ char smem[24576];
  char* As = smem;                       // [64][64]
  char* Bs = smem + 8192;                // [128][64]
  const int tid = threadIdx.x, lane = tid & 63, w = tid >> 6;
  const int frow = lane & 15, fk = lane >> 4;
  const int wr = (w >> 1) * 32, wc = (w & 1) * 64;
  const int m0 = blockIdx.x * 64, n0 = blockIdx.y * 128;
  const u16* Ap = Y + m0 * DM;
  const u16* Bp = Wot + n0 * DM;
  const int ro = lane >> 3;
  const int ce = ((lane & 7) ^ ro) << 3;

  f32x4 acc[2][4];
#pragma unroll
  for (int mi = 0; mi < 2; ++mi)
#pragma unroll
    for (int ni = 0; ni < 4; ++ni) acc[mi][ni] = (f32x4){0.f, 0.f, 0.f, 0.f};

  for (int k0 = 0; k0 < DM; k0 += 64) {
#pragma unroll
    for (int c = 0; c < 2; ++c) {
      const int g8 = (w * 2 + c) * 8;
      gll16(Ap + (g8 + ro) * DM + k0 + ce, As + g8 * 128);
    }
#pragma unroll
    for (int c = 0; c < 4; ++c) {
      const int g8 = (w * 4 + c) * 8;
      gll16(Bp + (g8 + ro) * DM + k0 + ce, Bs + g8 * 128);
    }
    asm volatile("s_waitcnt vmcnt(0)" ::: "memory");
    __syncthreads();
    bf16x8 a[2][2], b[4][2];
#pragma unroll
    for (int mi = 0; mi < 2; ++mi)
#pragma unroll
      for (int kk = 0; kk < 2; ++kk)
        a[mi][kk] = ldf(As, wr + mi * 16 + frow, kk * 4 + fk);
#pragma unroll
    for (int ni = 0; ni < 4; ++ni)
#pragma unroll
      for (int kk = 0; kk < 2; ++kk)
        b[ni][kk] = ldf(Bs, wc + ni * 16 + frow, kk * 4 + fk);
#pragma unroll
    for (int mi = 0; mi < 2; ++mi)
#pragma unroll
      for (int ni = 0; ni < 4; ++ni)
#pragma unroll
        for (int kk = 0; kk < 2; ++kk)
          acc[mi][ni] = __builtin_amdgcn_mfma_f32_16x16x32_bf16(
              a[mi][kk], b[ni][kk], acc[mi][ni], 0, 0, 0);
    __syncthreads();
  }
#pragma unroll
  for (int mi = 0; mi < 2; ++mi)
#pragma unroll
    for (int ni = 0; ni < 4; ++ni)
#pragma unroll
      for (int r = 0; r < 4; ++r) {
        int m = m0 + wr + mi * 16 + fk * 4 + r;
        int n = n0 + wc + ni * 16 + frow;
        out[m * DM + n] = acc[mi][ni][r] + bo[n];
      }
}

// ---------------- flash attention (causal), swapped-operand 32x32 ----------
__global__ __launch_bounds__(256) void k_attn(
    const u16* __restrict__ Qg, const u16* __restrict__ Kg,
    const u16* __restrict__ Vtg, u16* __restrict__ Yg) {
  __shared__ char Kl[64 * 128];   // [j][d] bf16, swizzled
  __shared__ char Vl[64 * 128];   // [d][j] bf16, swizzled
  const int bh = blockIdx.x;
  const int qt = 15 - blockIdx.y;         // long-first (LPT) remap
  const int q0 = qt * 128;
  const int tid = threadIdx.x, w = tid >> 6, lane = tid & 63;
  const int hi = lane >> 5, qq = lane & 31;
  const u16* Qb = Qg + bh * (T_ * DH);
  const u16* Kb = Kg + bh * (T_ * DH);
  const u16* Vb = Vtg + bh * (DH * T_);
  const int qrow = q0 + w * 32 + qq;

  bf16x8 qf[4];
#pragma unroll
  for (int kb = 0; kb < 4; ++kb)
    qf[kb] = *(const bf16x8*)(Qb + qrow * DH + kb * 16 + hi * 8);

  f32x16 o0, o1;
#pragma unroll
  for (int r = 0; r < 16; ++r) { o0[r] = 0.f; o1[r] = 0.f; }
  float m = -1e30f, lp = 0.f;

  const int nt = 2 * qt + 2;
  const int nfull = 2 * qt + (w >> 1);
  const int sr = tid >> 3, sc = tid & 7;
  const int swz0 = (sr * 128 + sc * 16) ^ ((sr & 7) << 4);
  const int swz1 = ((sr + 32) * 128 + sc * 16) ^ ((sr & 7) << 4);

  u32x4 kr0 = *(const u32x4*)(Kb + sr * DH + sc * 8);
  u32x4 kr1 = *(const u32x4*)(Kb + (sr + 32) * DH + sc * 8);
  u32x4 vr0 = *(const u32x4*)(Vb + sr * T_ + sc * 8);
  u32x4 vr1 = *(const u32x4*)(Vb + (sr + 32) * T_ + sc * 8);

  for (int t = 0; t < nt; ++t) {
    __syncthreads();
    *(u32x4*)(Kl + swz0) = kr0;
    *(u32x4*)(Kl + swz1) = kr1;
    *(u32x4*)(Vl + swz0) = vr0;
    *(u32x4*)(Vl + swz1) = vr1;
    __syncthreads();
    if (t + 1 < nt) {
      const int jn = (t + 1) * 64;
      kr0 = *(const u32x4*)(Kb + (jn + sr) * DH + sc * 8);
      kr1 = *(const u32x4*)(Kb + (jn + sr + 32) * DH + sc * 8);
      vr0 = *(const u32x4*)(Vb + sr * T_ + jn + sc * 8);
      vr1 = *(const u32x4*)(Vb + (sr + 32) * T_ + jn + sc * 8);
    }
    if (t > nfull) continue;
    const int j0 = t * 64;

    f32x16 s0, s1;
#pragma unroll
    for (int r = 0; r < 16; ++r) { s0[r] = 0.f; s1[r] = 0.f; }
#pragma unroll
    for (int kb = 0; kb < 4; ++kb) {
      const int cb = (kb * 2 + hi) * 16;
      bf16x8 ka0 = *(const bf16x8*)(Kl + ((qq * 128 + cb) ^ ((qq & 7) << 4)));
      s0 = __builtin_amdgcn_mfma_f32_32x32x16_bf16(ka0, qf[kb], s0, 0, 0, 0);
      bf16x8 ka1 =
          *(const bf16x8*)(Kl + (((qq + 32) * 128 + cb) ^ ((qq & 7) << 4)));
      s1 = __builtin_amdgcn_mfma_f32_32x32x16_bf16(ka1, qf[kb], s1, 0, 0, 0);
    }
    if (t == nfull) {
#pragma unroll
      for (int r = 0; r < 16; ++r) {
        const int cr = (r & 3) + 8 * (r >> 2) + 4 * hi;
        if (j0 + cr > qrow) s0[r] = -1e30f;
        if (j0 + 32 + cr > qrow) s1[r] = -1e30f;
      }
    }
    float mt = s0[0];
#pragma unroll
    for (int r = 1; r < 16; ++r) mt = fmaxf(mt, s0[r]);
#pragma unroll
    for (int r = 0; r < 16; ++r) mt = fmaxf(mt, s1[r]);
    mt = fmaxf(mt, __shfl_xor(mt, 32));
    if (__any(mt > m + 8.f)) {
      const float mn = fmaxf(m, mt);
      const float al = __builtin_amdgcn_exp2f(m - mn);
      m = mn;
#pragma unroll
      for (int r = 0; r < 16; ++r) { o0[r] *= al; o1[r] *= al; }
      lp *= al;
    }
#pragma unroll
    for (int r = 0; r < 16; ++r) {
      s0[r] = __builtin_amdgcn_exp2f(s0[r] - m);
      s1[r] = __builtin_amdgcn_exp2f(s1[r] - m);
    }
    float ps = 0.f;
#pragma unroll
    for (int r = 0; r < 16; ++r) ps += s0[r] + s1[r];
    lp += ps;
    bf16x8 pb[4];
#define MKCH(DST, S, RB)                                                     \
  {                                                                          \
    u32 a01 = cvtpk(S[RB + 0], S[RB + 1]);                                   \
    u32 a23 = cvtpk(S[RB + 2], S[RB + 3]);                                   \
    u32 a45 = cvtpk(S[RB + 4], S[RB + 5]);                                   \
    u32 a67 = cvtpk(S[RB + 6], S[RB + 7]);                                   \
    asm volatile("v_permlane32_swap_b32 %0, %1" : "+v"(a01), "+v"(a45));     \
    asm volatile("v_permlane32_swap_b32 %0, %1" : "+v"(a23), "+v"(a67));     \
    u32x4 t4;                                                                \
    t4[0] = a01; t4[1] = a23; t4[2] = a45; t4[3] = a67;                      \
    DST = __builtin_bit_cast(bf16x8, t4);                                    \
  }
    MKCH(pb[0], s0, 0)
    MKCH(pb[1], s0, 8)
    MKCH(pb[2], s1, 0)
    MKCH(pb[3], s1, 8)
#undef MKCH
#pragma unroll
    for (int jc = 0; jc < 4; ++jc) {
      const int cb = (jc * 2 + hi) * 16;
      bf16x8 va0 = *(const bf16x8*)(Vl + ((qq * 128 + cb) ^ ((qq & 7) << 4)));
      o0 = __builtin_amdgcn_mfma_f32_32x32x16_bf16(va0, pb[jc], o0, 0, 0, 0);
      bf16x8 va1 =
          *(const bf16x8*)(Vl + (((qq + 32) * 128 + cb) ^ ((qq & 7) << 4)));
      o1 = __builtin_amdgcn_mfma_f32_32x32x16_bf16(va1, pb[jc], o1, 0, 0, 0);
    }
  }
  lp += __shfl_xor(lp, 32);
  const float rl = 1.0f / lp;
  const int obase = ((bh >> 4) * T_ + qrow) * DM + (bh & 15) * DH;
#pragma unroll
  for (int g = 0; g < 4; ++g) {
    u32x2 st;
    st[0] = cvtpk(o0[g * 4 + 0] * rl, o0[g * 4 + 1] * rl);
    st[1] = cvtpk(o0[g * 4 + 2] * rl, o0[g * 4 + 3] * rl);
    *(u32x2*)(Yg + obase + g * 8 + hi * 4) = st;
    st[0] = cvtpk(o1[g * 4 + 0] * rl, o1[g * 4 + 1] * rl);
    st[1] = cvtpk(o1[g * 4 + 2] * rl, o1[g * 4 + 3] * rl);
    *(u32x2*)(Yg + obase + 32 + g * 8 + hi * 4) = st;
  }
}

// ---------------- launch ----------------

extern "C" void kernel_launch(void* const* d_in, const int* in_sizes, int n_in,
                              void* d_out, int out_size, void* d_ws,
                              size_t ws_size, hipStream_t stream) {
  const float* x  = (const float*)d_in[0];
  const float* Wq = (const float*)d_in[1];
  const float* Wk = (const float*)d_in[2];
  const float* Wv = (const float*)d_in[3];
  const float* Wo = (const float*)d_in[4];
  const float* bo = (const float*)d_in[5];
  float* out = (float*)d_out;
  char* ws = (char*)d_ws;

  u16* xb  = (u16*)(ws);                    // 8 MiB [4096][1024]
  u16* wqt = (u16*)(ws + (8ull << 20));     // 2 MiB each, [N][K]
  u16* wkt = (u16*)(ws + (10ull << 20));
  u16* wvt = (u16*)(ws + (12ull << 20));
  u16* wot = (u16*)(ws + (14ull << 20));
  u16* Qg  = (u16*)(ws + (16ull << 20));    // 8 MiB [b,h,t,d]
  u16* Kg  = (u16*)(ws + (24ull << 20));    // 8 MiB [b,h,t,d]
  u16* Vtg = (u16*)(ws + (32ull << 20));    // 8 MiB [b,h,d,t]
  u16* Yg  = (u16*)(ws + (40ull << 20));    // 8 MiB [4096][1024]

  k_cvt_x<<<2048, 256, 0, stream>>>(x, xb);
  k_cvt_wt<<<dim3(16, 16, 4), 256, 0, stream>>>(Wq, Wk, Wv, Wo, wqt, wkt, wvt, wot);
  k_qkv<<<dim3(32, 24), 256, 0, stream>>>(xb, wqt, wkt, wvt, Qg, Kg, Vtg);
  k_attn<<<dim3(32, 16), 256, 0, stream>>>(Qg, Kg, Vtg, Yg);
  k_out<<<dim3(64, 8), 256, 0, stream>>>(Yg, wot, bo, out);
}